// Round 1
// baseline (5904.910 us; speedup 1.0000x reference)
//
#include <hip/hip_runtime.h>
#include <cstdint>
#include <cstddef>

// Problem constants
#define B_DIM 8
#define NQ    1024
#define MK    1024
#define CD    640
#define INV_EPS 20.0f      // 1/0.05
#define EPS_OT  0.05f

static __device__ __forceinline__ float wave_reduce_sum(float s) {
#pragma unroll
  for (int off = 32; off; off >>= 1) s += __shfl_xor(s, off, 64);
  return s;
}

// ---------------------------------------------------------------------------
// Setup: detect mask dtype (u8 bool vs int32), build maskI, per-batch mu, w=1
// Single block so detection can sync before use.
// ---------------------------------------------------------------------------
__global__ void k_setup(const void* __restrict__ maskRaw, int* __restrict__ maskI,
                        float* __restrict__ muVal, float* __restrict__ w)
{
  __shared__ int s_flag;
  __shared__ int s_cnt[B_DIM];
  const int tid = threadIdx.x;
  if (tid == 0) s_flag = 0;
  if (tid < B_DIM) s_cnt[tid] = 0;
  __syncthreads();

  const unsigned char* mb = (const unsigned char*)maskRaw;
  int local = 0;
  for (int i = tid; i < B_DIM * MK; i += 1024)
    if ((i & 3) && mb[i]) local = 1;
  if (local) atomicOr(&s_flag, 1);
  __syncthreads();

  const int isByte = s_flag;           // nonzero high bytes => 1-byte bool layout
  const int* mi32 = (const int*)maskRaw;
  for (int i = tid; i < B_DIM * MK; i += 1024) {
    int v = isByte ? (int)mb[i] : mi32[i];
    v = v ? 1 : 0;
    maskI[i] = v;
    if (v) atomicAdd(&s_cnt[i >> 10], 1);
  }
  for (int i = tid; i < B_DIM * NQ; i += 1024) w[i] = 1.0f;
  __syncthreads();
  if (tid < B_DIM) {
    float c = (float)s_cnt[tid];
    muVal[tid] = (c > 0.f ? 1.0f / c : 1.0f / (float)MK) + 1e-8f;  // mu + 1e-8
  }
}

// ---------------------------------------------------------------------------
// Projection GEMM: out[perm(r)][c] = sum_k X[r][k]*W[c][k] + bias[c]
// X: 8192x640, W: 640x640 row-major. Tile 128x128, BK=32, 256 thr, 8x8/thread.
// MODE 0: orow=r (xk/xv). MODE 1: r=(n*8+b)->b*1024+n (xq). MODE 2: r=(b*1024+n)->n*8+b.
// ---------------------------------------------------------------------------
template<int MODE>
__global__ __launch_bounds__(256)
void gemm_proj(const float* __restrict__ X, const float* __restrict__ W,
               const float* __restrict__ bias, float* __restrict__ out)
{
  __shared__ float As[32 * 132];
  __shared__ float Bs[32 * 132];
  const int tid = threadIdx.x;
  const int row0 = blockIdx.x << 7;
  const int col0 = blockIdx.y << 7;
  const int ty = tid >> 4, tx = tid & 15;
  float acc[8][8];
#pragma unroll
  for (int i = 0; i < 8; ++i)
#pragma unroll
    for (int j = 0; j < 8; ++j) acc[i][j] = 0.f;

  for (int k0 = 0; k0 < CD; k0 += 32) {
    const float* Ap = X + (size_t)row0 * CD + k0;
    const float* Wp = W + (size_t)col0 * CD + k0;
#pragma unroll
    for (int t = 0; t < 4; ++t) {
      const int e = tid + (t << 8);
      const int r = e >> 3;
      const int kq = (e & 7) << 2;
      const float4 ga = *(const float4*)(Ap + (size_t)r * CD + kq);
      As[(kq + 0) * 132 + r] = ga.x;
      As[(kq + 1) * 132 + r] = ga.y;
      As[(kq + 2) * 132 + r] = ga.z;
      As[(kq + 3) * 132 + r] = ga.w;
      const float4 gb = *(const float4*)(Wp + (size_t)r * CD + kq);
      Bs[(kq + 0) * 132 + r] = gb.x;
      Bs[(kq + 1) * 132 + r] = gb.y;
      Bs[(kq + 2) * 132 + r] = gb.z;
      Bs[(kq + 3) * 132 + r] = gb.w;
    }
    __syncthreads();
#pragma unroll
    for (int k = 0; k < 32; ++k) {
      const float* ak = As + k * 132;
      const float* bk2 = Bs + k * 132;
      float a[8], b[8];
      *(float4*)(a)     = *(const float4*)(ak + (ty << 2));
      *(float4*)(a + 4) = *(const float4*)(ak + 64 + (ty << 2));
      *(float4*)(b)     = *(const float4*)(bk2 + (tx << 2));
      *(float4*)(b + 4) = *(const float4*)(bk2 + 64 + (tx << 2));
#pragma unroll
      for (int i = 0; i < 8; ++i)
#pragma unroll
        for (int j = 0; j < 8; ++j)
          acc[i][j] = fmaf(a[i], b[j], acc[i][j]);
    }
    __syncthreads();
  }
#pragma unroll
  for (int i = 0; i < 8; ++i) {
    const int rr = row0 + ((i < 4) ? ((ty << 2) + i) : (64 + (ty << 2) + i - 4));
    size_t orow;
    if (MODE == 0)      orow = (size_t)rr;
    else if (MODE == 1) orow = (size_t)(rr & 7) * NQ + (rr >> 3);
    else                orow = (size_t)(rr & (NQ - 1)) * B_DIM + (rr >> 10);
#pragma unroll
    for (int jh = 0; jh < 2; ++jh) {
      const int cc = col0 + (jh << 6) + (tx << 2);
      const float4 bv = *(const float4*)(bias + cc);
      float4 o;
      o.x = acc[i][jh * 4 + 0] + bv.x;
      o.y = acc[i][jh * 4 + 1] + bv.y;
      o.z = acc[i][jh * 4 + 2] + bv.z;
      o.w = acc[i][jh * 4 + 3] + bv.w;
      *(float4*)(out + orow * CD + cc) = o;
    }
  }
}

// ---------------------------------------------------------------------------
// l2norm over rows of 640 (one wave per row)
// ---------------------------------------------------------------------------
__global__ __launch_bounds__(256)
void k_l2norm(float* __restrict__ X)
{
  const int row = (blockIdx.x << 2) + (threadIdx.x >> 6);
  const int lane = threadIdx.x & 63;
  float2* p2 = (float2*)(X + (size_t)row * CD);
  float ss = 0.f;
#pragma unroll
  for (int i = 0; i < 5; ++i) {
    float2 v = p2[lane + (i << 6)];
    ss = fmaf(v.x, v.x, fmaf(v.y, v.y, ss));
  }
  ss = wave_reduce_sum(ss);
  const float inv = 1.0f / fmaxf(sqrtf(ss), 1e-12f);
#pragma unroll
  for (int i = 0; i < 5; ++i) {
    float2 v = p2[lane + (i << 6)];
    v.x *= inv; v.y *= inv;
    p2[lane + (i << 6)] = v;
  }
}

// ---------------------------------------------------------------------------
// sim GEMM (NT, batched): E[b][m][n] = exp((k[b][m]·q[b][n] - 1) * 20)
// ---------------------------------------------------------------------------
__global__ __launch_bounds__(256)
void gemm_sim(const float* __restrict__ kb, const float* __restrict__ qb,
              float* __restrict__ E)
{
  __shared__ float As[32 * 132];
  __shared__ float Bs[32 * 132];
  const int tid = threadIdx.x;
  const int b = blockIdx.z;
  const int row0 = blockIdx.x << 7;  // m
  const int col0 = blockIdx.y << 7;  // n
  const int ty = tid >> 4, tx = tid & 15;
  const float* A = kb + (size_t)b * MK * CD;
  const float* Bq = qb + (size_t)b * NQ * CD;
  float acc[8][8];
#pragma unroll
  for (int i = 0; i < 8; ++i)
#pragma unroll
    for (int j = 0; j < 8; ++j) acc[i][j] = 0.f;

  for (int k0 = 0; k0 < CD; k0 += 32) {
    const float* Ap = A + (size_t)row0 * CD + k0;
    const float* Bp = Bq + (size_t)col0 * CD + k0;
#pragma unroll
    for (int t = 0; t < 4; ++t) {
      const int e = tid + (t << 8);
      const int r = e >> 3;
      const int kq = (e & 7) << 2;
      const float4 ga = *(const float4*)(Ap + (size_t)r * CD + kq);
      As[(kq + 0) * 132 + r] = ga.x;
      As[(kq + 1) * 132 + r] = ga.y;
      As[(kq + 2) * 132 + r] = ga.z;
      As[(kq + 3) * 132 + r] = ga.w;
      const float4 gb = *(const float4*)(Bp + (size_t)r * CD + kq);
      Bs[(kq + 0) * 132 + r] = gb.x;
      Bs[(kq + 1) * 132 + r] = gb.y;
      Bs[(kq + 2) * 132 + r] = gb.z;
      Bs[(kq + 3) * 132 + r] = gb.w;
    }
    __syncthreads();
#pragma unroll
    for (int k = 0; k < 32; ++k) {
      const float* ak = As + k * 132;
      const float* bk2 = Bs + k * 132;
      float a[8], bb[8];
      *(float4*)(a)      = *(const float4*)(ak + (ty << 2));
      *(float4*)(a + 4)  = *(const float4*)(ak + 64 + (ty << 2));
      *(float4*)(bb)     = *(const float4*)(bk2 + (tx << 2));
      *(float4*)(bb + 4) = *(const float4*)(bk2 + 64 + (tx << 2));
#pragma unroll
      for (int i = 0; i < 8; ++i)
#pragma unroll
        for (int j = 0; j < 8; ++j)
          acc[i][j] = fmaf(a[i], bb[j], acc[i][j]);
    }
    __syncthreads();
  }
#pragma unroll
  for (int i = 0; i < 8; ++i) {
    const int rr = row0 + ((i < 4) ? ((ty << 2) + i) : (64 + (ty << 2) + i - 4));
    const size_t ebase = ((size_t)b * MK + rr) * NQ;
#pragma unroll
    for (int jh = 0; jh < 2; ++jh) {
      const int cc = col0 + (jh << 6) + (tx << 2);
      float4 o;
      o.x = __expf((acc[i][jh * 4 + 0] - 1.f) * INV_EPS);
      o.y = __expf((acc[i][jh * 4 + 1] - 1.f) * INV_EPS);
      o.z = __expf((acc[i][jh * 4 + 2] - 1.f) * INV_EPS);
      o.w = __expf((acc[i][jh * 4 + 3] - 1.f) * INV_EPS);
      *(float4*)(E + ebase + cc) = o;
    }
  }
}

// ---------------------------------------------------------------------------
// Sinkhorn u-phase: z[b][m] = mu_eff / sum_n E[b][m][n]*w[b][n]; masked -> 0
// One wave per row; masked rows skip the 4KB read entirely.
// ---------------------------------------------------------------------------
__global__ __launch_bounds__(256)
void k_uphase(const float* __restrict__ E, const float* __restrict__ w,
              float* __restrict__ z, const int* __restrict__ maskI,
              const float* __restrict__ muVal)
{
  const int row = (blockIdx.x << 2) + (threadIdx.x >> 6);
  const int lane = threadIdx.x & 63;
  if (!maskI[row]) { if (!lane) z[row] = 0.f; return; }
  const int b = row >> 10;
  const float4* Er = (const float4*)(E + ((size_t)row << 10));
  const float4* wr = (const float4*)(w + (b << 10));
  float s = 0.f;
#pragma unroll
  for (int t = 0; t < 4; ++t) {
    const float4 e = Er[lane + (t << 6)];
    const float4 ww = wr[lane + (t << 6)];
    s += e.x * ww.x + e.y * ww.y + e.z * ww.z + e.w * ww.w;
  }
  s = wave_reduce_sum(s);
  if (!lane) z[row] = muVal[b] / fmaxf(s, 1e-35f);
}

// ---------------------------------------------------------------------------
// Sinkhorn v-phase: w[b][n] = nu_eff / sum_{m valid} E[b][m][n]*z[b][m]
// Block handles 32 n; 8 m-groups; z==0 rows skipped (saves the load).
// ---------------------------------------------------------------------------
__global__ __launch_bounds__(256)
void k_vphase(const float* __restrict__ E, const float* __restrict__ z,
              float* __restrict__ w)
{
  __shared__ float red[8][33];
  const int b = blockIdx.y;
  const int n0 = blockIdx.x << 5;
  const int ni = threadIdx.x & 31, mi = threadIdx.x >> 5;
  const float* Eb = E + ((size_t)b << 20);
  const float* zb = z + (b << 10);
  float s = 0.f;
  for (int m = mi; m < MK; m += 8) {
    const float zm = zb[m];
    if (zm != 0.f) s = fmaf(Eb[((size_t)m << 10) + n0 + ni], zm, s);
  }
  red[mi][ni] = s;
  __syncthreads();
  if (threadIdx.x < 32) {
    float t = 0.f;
#pragma unroll
    for (int j = 0; j < 8; ++j) t += red[j][threadIdx.x];
    const float nuEff = 1.0f / (float)NQ + 1e-8f;
    w[(b << 10) + n0 + threadIdx.x] = nuEff / fmaxf(t, 1e-35f);
  }
}

// ---------------------------------------------------------------------------
// attn_save[b][m] = M*Nq * z[m] * sum_n (1 + eps*ln(E)) * E * w[n]; masked -> 0
// ---------------------------------------------------------------------------
__global__ __launch_bounds__(256)
void k_attn(const float* __restrict__ E, const float* __restrict__ w,
            const float* __restrict__ z, const int* __restrict__ maskI,
            float* __restrict__ attn)
{
  const int row = (blockIdx.x << 2) + (threadIdx.x >> 6);
  const int lane = threadIdx.x & 63;
  if (!maskI[row]) { if (!lane) attn[row] = 0.f; return; }
  const int b = row >> 10;
  const float4* Er = (const float4*)(E + ((size_t)row << 10));
  const float4* wr = (const float4*)(w + (b << 10));
  float s = 0.f;
#pragma unroll
  for (int t = 0; t < 4; ++t) {
    const float4 e = Er[lane + (t << 6)];
    const float4 ww = wr[lane + (t << 6)];
    s += (1.f + EPS_OT * __logf(e.x)) * e.x * ww.x;
    s += (1.f + EPS_OT * __logf(e.y)) * e.y * ww.y;
    s += (1.f + EPS_OT * __logf(e.z)) * e.z * ww.z;
    s += (1.f + EPS_OT * __logf(e.w)) * e.w * ww.w;
  }
  s = wave_reduce_sum(s);
  if (!lane) attn[row] = (float)(MK) * (float)(NQ) * z[row] * s;
}

// ---------------------------------------------------------------------------
// x GEMM: xb[b][n][c] = w[b][n] * sum_m (z[b][m]*E[b][m][n]) * v[b][m][c]
// Tile 128(n) x 128(c), K = m in steps of 32. No LDS transpose needed.
// ---------------------------------------------------------------------------
__global__ __launch_bounds__(256)
void gemm_x(const float* __restrict__ E, const float* __restrict__ vb,
            const float* __restrict__ z, const float* __restrict__ w,
            float* __restrict__ xb)
{
  __shared__ float Ts[32 * 132];
  __shared__ float Vs[32 * 132];
  const int tid = threadIdx.x;
  const int b = blockIdx.z;
  const int n0 = blockIdx.x << 7;
  const int c0 = blockIdx.y << 7;
  const int ty = tid >> 4, tx = tid & 15;
  const float* Eb = E + ((size_t)b << 20);
  const float* Vb = vb + (size_t)b * MK * CD;
  const float* zb = z + (b << 10);
  float acc[8][8];
#pragma unroll
  for (int i = 0; i < 8; ++i)
#pragma unroll
    for (int j = 0; j < 8; ++j) acc[i][j] = 0.f;

  for (int m0 = 0; m0 < MK; m0 += 32) {
#pragma unroll
    for (int t = 0; t < 4; ++t) {
      const int e = tid + (t << 8);
      const int c4 = (e & 31) << 2;
      const int k = e >> 5;
      const float zk = zb[m0 + k];
      const float4 g = *(const float4*)(Eb + ((size_t)(m0 + k) << 10) + n0 + c4);
      float4 tv;
      tv.x = g.x * zk; tv.y = g.y * zk; tv.z = g.z * zk; tv.w = g.w * zk;
      *(float4*)(Ts + k * 132 + c4) = tv;
      const float4 gv = *(const float4*)(Vb + (size_t)(m0 + k) * CD + c0 + c4);
      *(float4*)(Vs + k * 132 + c4) = gv;
    }
    __syncthreads();
#pragma unroll
    for (int k = 0; k < 32; ++k) {
      const float* ak = Ts + k * 132;
      const float* bk2 = Vs + k * 132;
      float a[8], bb[8];
      *(float4*)(a)      = *(const float4*)(ak + (ty << 2));
      *(float4*)(a + 4)  = *(const float4*)(ak + 64 + (ty << 2));
      *(float4*)(bb)     = *(const float4*)(bk2 + (tx << 2));
      *(float4*)(bb + 4) = *(const float4*)(bk2 + 64 + (tx << 2));
#pragma unroll
      for (int i = 0; i < 8; ++i)
#pragma unroll
        for (int j = 0; j < 8; ++j)
          acc[i][j] = fmaf(a[i], bb[j], acc[i][j]);
    }
    __syncthreads();
  }
#pragma unroll
  for (int i = 0; i < 8; ++i) {
    const int nrow = n0 + ((i < 4) ? ((ty << 2) + i) : (64 + (ty << 2) + i - 4));
    const float wn = w[(b << 10) + nrow];
    const size_t obase = ((size_t)(b << 10) + nrow) * CD;
#pragma unroll
    for (int jh = 0; jh < 2; ++jh) {
      const int cc = c0 + (jh << 6) + (tx << 2);
      float4 o;
      o.x = acc[i][jh * 4 + 0] * wn;
      o.y = acc[i][jh * 4 + 1] * wn;
      o.z = acc[i][jh * 4 + 2] * wn;
      o.w = acc[i][jh * 4 + 3] * wn;
      *(float4*)(xb + obase + cc) = o;
    }
  }
}

// ---------------------------------------------------------------------------
extern "C" void kernel_launch(void* const* d_in, const int* in_sizes, int n_in,
                              void* d_out, int out_size, void* d_ws, size_t ws_size,
                              hipStream_t stream)
{
  const float* xq = (const float*)d_in[0];
  const float* xk = (const float*)d_in[1];
  const float* xv = (const float*)d_in[2];
  const void*  maskRaw = d_in[3];
  const float* Wq = (const float*)d_in[4];
  const float* bq = (const float*)d_in[5];
  const float* Wk = (const float*)d_in[6];
  const float* bk = (const float*)d_in[7];
  const float* Wv = (const float*)d_in[8];
  const float* bv = (const float*)d_in[9];
  const float* Wp = (const float*)d_in[10];
  const float* bp = (const float*)d_in[11];

  float* out  = (float*)d_out;
  float* attn = out + (size_t)NQ * B_DIM * CD;

  float* qb = (float*)d_ws;                       // [B][Nq][C], reused as xb later
  float* kb = qb + (size_t)B_DIM * NQ * CD;       // [B][M][C]
  float* vb = kb + (size_t)B_DIM * MK * CD;       // [B][M][C]
  float* E  = vb + (size_t)B_DIM * MK * CD;       // [B][M][Nq]
  float* z  = E + (size_t)B_DIM * MK * NQ;        // [B][M]
  float* w  = z + B_DIM * MK;                     // [B][Nq]
  int* maskI   = (int*)(w + B_DIM * NQ);          // [B][M]
  float* muVal = (float*)(maskI + B_DIM * MK);    // [B]
  float* xb = qb;

  k_setup<<<1, 1024, 0, stream>>>(maskRaw, maskI, muVal, w);

  gemm_proj<1><<<dim3(64, 5), 256, 0, stream>>>(xq, Wq, bq, qb);
  gemm_proj<0><<<dim3(64, 5), 256, 0, stream>>>(xk, Wk, bk, kb);
  gemm_proj<0><<<dim3(64, 5), 256, 0, stream>>>(xv, Wv, bv, vb);
  k_l2norm<<<2048, 256, 0, stream>>>(qb);
  k_l2norm<<<2048, 256, 0, stream>>>(kb);

  gemm_sim<<<dim3(8, 8, 8), 256, 0, stream>>>(kb, qb, E);

  for (int it = 0; it < 100; ++it) {
    k_uphase<<<2048, 256, 0, stream>>>(E, w, z, maskI, muVal);
    k_vphase<<<dim3(32, 8), 256, 0, stream>>>(E, z, w);
  }

  k_attn<<<2048, 256, 0, stream>>>(E, w, z, maskI, attn);
  gemm_x<<<dim3(8, 5, 8), 256, 0, stream>>>(E, vb, z, w, xb);
  gemm_proj<2><<<dim3(64, 5), 256, 0, stream>>>(xb, Wp, bp, out);
}

// Round 2
// 5761.472 us; speedup vs baseline: 1.0249x; 1.0249x over previous
//
#include <hip/hip_runtime.h>
#include <cstdint>
#include <cstddef>

#define B_DIM 8
#define NQ    1024
#define MK    1024
#define CD    640
#define INV_EPS 20.0f
#define EPS_OT  0.05f

static __device__ __forceinline__ float wave_reduce_sum(float s) {
#pragma unroll
  for (int off = 32; off; off >>= 1) s += __shfl_xor(s, off, 64);
  return s;
}

// ---------------------------------------------------------------------------
// Setup: detect mask dtype, build maskI, per-batch mu, w=1, zero barrier ctrs
// ---------------------------------------------------------------------------
__global__ void k_setup(const void* __restrict__ maskRaw, int* __restrict__ maskI,
                        float* __restrict__ muVal, float* __restrict__ w,
                        unsigned* __restrict__ barCtr)
{
  __shared__ int s_flag;
  __shared__ int s_cnt[B_DIM];
  const int tid = threadIdx.x;
  if (tid == 0) s_flag = 0;
  if (tid < B_DIM) s_cnt[tid] = 0;
  if (tid < 256) barCtr[tid] = 0u;
  __syncthreads();

  const unsigned char* mb = (const unsigned char*)maskRaw;
  int local = 0;
  for (int i = tid; i < B_DIM * MK; i += 1024)
    if ((i & 3) && mb[i]) local = 1;
  if (local) atomicOr(&s_flag, 1);
  __syncthreads();

  const int isByte = s_flag;
  const int* mi32 = (const int*)maskRaw;
  for (int i = tid; i < B_DIM * MK; i += 1024) {
    int v = isByte ? (int)mb[i] : mi32[i];
    v = v ? 1 : 0;
    maskI[i] = v;
    if (v) atomicAdd(&s_cnt[i >> 10], 1);
  }
  for (int i = tid; i < B_DIM * NQ; i += 1024) w[i] = 1.0f;
  __syncthreads();
  if (tid < B_DIM) {
    float c = (float)s_cnt[tid];
    muVal[tid] = (c > 0.f ? 1.0f / c : 1.0f / (float)MK) + 1e-8f;
  }
}

// ---------------------------------------------------------------------------
// A = Wp @ Wv  (A[c][k] = sum_j Wp[c][j]*Wv[j][k]), 640x640. 64x64 tiles.
// ---------------------------------------------------------------------------
__global__ __launch_bounds__(256)
void k_combineA(const float* __restrict__ Wp, const float* __restrict__ Wv,
                float* __restrict__ A)
{
  __shared__ float Ps[32][68];   // Ps[j][c]
  __shared__ float Vs[32][68];   // Vs[j][k]
  const int tid = threadIdx.x;
  const int c0 = blockIdx.x << 6, k0 = blockIdx.y << 6;
  const int ty = tid >> 4, tx = tid & 15;
  float acc[4][4];
#pragma unroll
  for (int i = 0; i < 4; ++i)
#pragma unroll
    for (int j = 0; j < 4; ++j) acc[i][j] = 0.f;

  for (int j0 = 0; j0 < CD; j0 += 32) {
    {
      const int c = tid >> 2, j4 = (tid & 3) << 3;
      const float* p = Wp + (size_t)(c0 + c) * CD + j0 + j4;
      float4 u0 = *(const float4*)p, u1 = *(const float4*)(p + 4);
      Ps[j4 + 0][c] = u0.x; Ps[j4 + 1][c] = u0.y; Ps[j4 + 2][c] = u0.z; Ps[j4 + 3][c] = u0.w;
      Ps[j4 + 4][c] = u1.x; Ps[j4 + 5][c] = u1.y; Ps[j4 + 6][c] = u1.z; Ps[j4 + 7][c] = u1.w;
    }
    {
      const int j = tid >> 3, k4 = (tid & 7) << 3;
      const float* p = Wv + (size_t)(j0 + j) * CD + k0 + k4;
      float4 u0 = *(const float4*)p, u1 = *(const float4*)(p + 4);
      *(float4*)&Vs[j][k4] = u0; *(float4*)&Vs[j][k4 + 4] = u1;
    }
    __syncthreads();
#pragma unroll
    for (int j = 0; j < 32; ++j) {
      float a[4], b[4];
      *(float4*)a = *(const float4*)&Ps[j][ty << 2];
      *(float4*)b = *(const float4*)&Vs[j][tx << 2];
#pragma unroll
      for (int i = 0; i < 4; ++i)
#pragma unroll
        for (int jj = 0; jj < 4; ++jj)
          acc[i][jj] = fmaf(a[i], b[jj], acc[i][jj]);
    }
    __syncthreads();
  }
#pragma unroll
  for (int i = 0; i < 4; ++i) {
    float4 o; o.x = acc[i][0]; o.y = acc[i][1]; o.z = acc[i][2]; o.w = acc[i][3];
    *(float4*)(A + (size_t)(c0 + (ty << 2) + i) * CD + k0 + (tx << 2)) = o;
  }
}

// bvp[c] = sum_j Wp[c][j]*bv[j]
__global__ __launch_bounds__(256)
void k_bvp(const float* __restrict__ Wp, const float* __restrict__ bv,
           float* __restrict__ bvp)
{
  const int c = (blockIdx.x << 2) + (threadIdx.x >> 6);
  const int lane = threadIdx.x & 63;
  float s = 0.f;
  for (int j = lane; j < CD; j += 64) s = fmaf(Wp[(size_t)c * CD + j], bv[j], s);
  s = wave_reduce_sum(s);
  if (!lane) bvp[c] = s;
}

// ---------------------------------------------------------------------------
// Merged projections: z=0: qb = perm(xq@Wq.T+bq); z=1: kb = xk@Wk.T+bk;
//                     z=2: vpb = xv@A.T-ish (+bvp)   [A row-major [c][k]]
// 128x128 tiles, grid (64,5,3) = 960 blocks.
// ---------------------------------------------------------------------------
__global__ __launch_bounds__(256)
void gemm_proj3(const float* __restrict__ xq, const float* __restrict__ xk,
                const float* __restrict__ xv,
                const float* __restrict__ Wq, const float* __restrict__ bq,
                const float* __restrict__ Wk, const float* __restrict__ bk,
                const float* __restrict__ Wvp, const float* __restrict__ bvp,
                float* __restrict__ qb, float* __restrict__ kb,
                float* __restrict__ vpb)
{
  __shared__ float As[32 * 132];
  __shared__ float Bs[32 * 132];
  const int mode = blockIdx.z;
  const float* X    = (mode == 0) ? xq  : ((mode == 1) ? xk : xv);
  const float* W    = (mode == 0) ? Wq  : ((mode == 1) ? Wk : Wvp);
  const float* bias = (mode == 0) ? bq  : ((mode == 1) ? bk : bvp);
  float* out        = (mode == 0) ? qb  : ((mode == 1) ? kb : vpb);

  const int tid = threadIdx.x;
  const int row0 = blockIdx.x << 7;
  const int col0 = blockIdx.y << 7;
  const int ty = tid >> 4, tx = tid & 15;
  float acc[8][8];
#pragma unroll
  for (int i = 0; i < 8; ++i)
#pragma unroll
    for (int j = 0; j < 8; ++j) acc[i][j] = 0.f;

  for (int k0 = 0; k0 < CD; k0 += 32) {
    const float* Ap = X + (size_t)row0 * CD + k0;
    const float* Wp2 = W + (size_t)col0 * CD + k0;
#pragma unroll
    for (int t = 0; t < 4; ++t) {
      const int e = tid + (t << 8);
      const int r = e >> 3;
      const int kq = (e & 7) << 2;
      const float4 ga = *(const float4*)(Ap + (size_t)r * CD + kq);
      As[(kq + 0) * 132 + r] = ga.x;
      As[(kq + 1) * 132 + r] = ga.y;
      As[(kq + 2) * 132 + r] = ga.z;
      As[(kq + 3) * 132 + r] = ga.w;
      const float4 gb = *(const float4*)(Wp2 + (size_t)r * CD + kq);
      Bs[(kq + 0) * 132 + r] = gb.x;
      Bs[(kq + 1) * 132 + r] = gb.y;
      Bs[(kq + 2) * 132 + r] = gb.z;
      Bs[(kq + 3) * 132 + r] = gb.w;
    }
    __syncthreads();
#pragma unroll
    for (int k = 0; k < 32; ++k) {
      const float* ak = As + k * 132;
      const float* bk2 = Bs + k * 132;
      float a[8], b[8];
      *(float4*)(a)     = *(const float4*)(ak + (ty << 2));
      *(float4*)(a + 4) = *(const float4*)(ak + 64 + (ty << 2));
      *(float4*)(b)     = *(const float4*)(bk2 + (tx << 2));
      *(float4*)(b + 4) = *(const float4*)(bk2 + 64 + (tx << 2));
#pragma unroll
      for (int i = 0; i < 8; ++i)
#pragma unroll
        for (int j = 0; j < 8; ++j)
          acc[i][j] = fmaf(a[i], b[j], acc[i][j]);
    }
    __syncthreads();
  }
#pragma unroll
  for (int i = 0; i < 8; ++i) {
    const int rr = row0 + ((i < 4) ? ((ty << 2) + i) : (64 + (ty << 2) + i - 4));
    size_t orow;
    if (mode == 0) orow = (size_t)(rr & 7) * NQ + (rr >> 3);
    else           orow = (size_t)rr;
#pragma unroll
    for (int jh = 0; jh < 2; ++jh) {
      const int cc = col0 + (jh << 6) + (tx << 2);
      const float4 bv4 = *(const float4*)(bias + cc);
      float4 o;
      o.x = acc[i][jh * 4 + 0] + bv4.x;
      o.y = acc[i][jh * 4 + 1] + bv4.y;
      o.z = acc[i][jh * 4 + 2] + bv4.z;
      o.w = acc[i][jh * 4 + 3] + bv4.w;
      *(float4*)(out + orow * CD + cc) = o;
    }
  }
}

// ---------------------------------------------------------------------------
// l2norm over rows of 640 (one wave per row); covers qb+kb in one launch
// ---------------------------------------------------------------------------
__global__ __launch_bounds__(256)
void k_l2norm(float* __restrict__ X)
{
  const int row = (blockIdx.x << 2) + (threadIdx.x >> 6);
  const int lane = threadIdx.x & 63;
  float2* p2 = (float2*)(X + (size_t)row * CD);
  float ss = 0.f;
#pragma unroll
  for (int i = 0; i < 5; ++i) {
    float2 v = p2[lane + (i << 6)];
    ss = fmaf(v.x, v.x, fmaf(v.y, v.y, ss));
  }
  ss = wave_reduce_sum(ss);
  const float inv = 1.0f / fmaxf(sqrtf(ss), 1e-12f);
#pragma unroll
  for (int i = 0; i < 5; ++i) {
    float2 v = p2[lane + (i << 6)];
    v.x *= inv; v.y *= inv;
    p2[lane + (i << 6)] = v;
  }
}

// ---------------------------------------------------------------------------
// sim GEMM (NT, batched): E[b][m][n] = exp((k[b][m]·q[b][n] - 1) * 20)
// ---------------------------------------------------------------------------
__global__ __launch_bounds__(256)
void gemm_sim(const float* __restrict__ kb, const float* __restrict__ qb,
              float* __restrict__ E)
{
  __shared__ float As[32 * 132];
  __shared__ float Bs[32 * 132];
  const int tid = threadIdx.x;
  const int b = blockIdx.z;
  const int row0 = blockIdx.x << 7;
  const int col0 = blockIdx.y << 7;
  const int ty = tid >> 4, tx = tid & 15;
  const float* A = kb + (size_t)b * MK * CD;
  const float* Bq = qb + (size_t)b * NQ * CD;
  float acc[8][8];
#pragma unroll
  for (int i = 0; i < 8; ++i)
#pragma unroll
    for (int j = 0; j < 8; ++j) acc[i][j] = 0.f;

  for (int k0 = 0; k0 < CD; k0 += 32) {
    const float* Ap = A + (size_t)row0 * CD + k0;
    const float* Bp = Bq + (size_t)col0 * CD + k0;
#pragma unroll
    for (int t = 0; t < 4; ++t) {
      const int e = tid + (t << 8);
      const int r = e >> 3;
      const int kq = (e & 7) << 2;
      const float4 ga = *(const float4*)(Ap + (size_t)r * CD + kq);
      As[(kq + 0) * 132 + r] = ga.x;
      As[(kq + 1) * 132 + r] = ga.y;
      As[(kq + 2) * 132 + r] = ga.z;
      As[(kq + 3) * 132 + r] = ga.w;
      const float4 gb = *(const float4*)(Bp + (size_t)r * CD + kq);
      Bs[(kq + 0) * 132 + r] = gb.x;
      Bs[(kq + 1) * 132 + r] = gb.y;
      Bs[(kq + 2) * 132 + r] = gb.z;
      Bs[(kq + 3) * 132 + r] = gb.w;
    }
    __syncthreads();
#pragma unroll
    for (int k = 0; k < 32; ++k) {
      const float* ak = As + k * 132;
      const float* bk2 = Bs + k * 132;
      float a[8], bb[8];
      *(float4*)(a)      = *(const float4*)(ak + (ty << 2));
      *(float4*)(a + 4)  = *(const float4*)(ak + 64 + (ty << 2));
      *(float4*)(bb)     = *(const float4*)(bk2 + (tx << 2));
      *(float4*)(bb + 4) = *(const float4*)(bk2 + 64 + (tx << 2));
#pragma unroll
      for (int i = 0; i < 8; ++i)
#pragma unroll
        for (int j = 0; j < 8; ++j)
          acc[i][j] = fmaf(a[i], bb[j], acc[i][j]);
    }
    __syncthreads();
  }
#pragma unroll
  for (int i = 0; i < 8; ++i) {
    const int rr = row0 + ((i < 4) ? ((ty << 2) + i) : (64 + (ty << 2) + i - 4));
    const size_t ebase = ((size_t)b * MK + rr) * NQ;
#pragma unroll
    for (int jh = 0; jh < 2; ++jh) {
      const int cc = col0 + (jh << 6) + (tx << 2);
      float4 o;
      o.x = __expf((acc[i][jh * 4 + 0] - 1.f) * INV_EPS);
      o.y = __expf((acc[i][jh * 4 + 1] - 1.f) * INV_EPS);
      o.z = __expf((acc[i][jh * 4 + 2] - 1.f) * INV_EPS);
      o.w = __expf((acc[i][jh * 4 + 3] - 1.f) * INV_EPS);
      *(float4*)(E + ebase + cc) = o;
    }
  }
}

// ---------------------------------------------------------------------------
// Fused persistent Sinkhorn: 512 WGs (64 per batch), 16 E-rows per WG held in
// registers (e[4][16] per lane, lane-strided cols). 100 iters, 2 per-batch
// spin barriers per iter. Ends with attn + z writeout.
// ---------------------------------------------------------------------------
__device__ __forceinline__ void wg_barrier(unsigned* ctr, unsigned target) {
  __syncthreads();                 // compiler drains vmcnt here -> stores in L2
  if (threadIdx.x == 0) {
    __threadfence();               // agent release: L2 writeback
    atomicAdd(ctr, 1u);
    while (__hip_atomic_load(ctr, __ATOMIC_ACQUIRE, __HIP_MEMORY_SCOPE_AGENT) < target)
      __builtin_amdgcn_s_sleep(2);
  }
  __syncthreads();
}

__global__ __launch_bounds__(256)
void k_sinkhorn(const float* __restrict__ E, const int* __restrict__ maskI,
                const float* __restrict__ muVal, float* __restrict__ w,
                float* __restrict__ z, float* __restrict__ attn,
                float* __restrict__ colPart, unsigned* __restrict__ barCtr)
{
  const int b = blockIdx.x >> 6;
  const int g = blockIdx.x & 63;
  const int tid = threadIdx.x;
  const int wave = tid >> 6, lane = tid & 63;
  const int m0 = (g << 4) + (wave << 2);
  const float* Eb = E + ((size_t)b << 20);
  float* wb = w + (b << 10);
  float* cpB = colPart + ((size_t)b << 16);
  unsigned* ctr = barCtr + b * 32;

  __shared__ float wS[1024];
  __shared__ float colRed[4][1024];

  float e[4][16];
#pragma unroll
  for (int r = 0; r < 4; ++r) {
    const float* row = Eb + ((size_t)(m0 + r) << 10) + lane;
#pragma unroll
    for (int j = 0; j < 16; ++j) e[r][j] = row[j << 6];
  }
  float rmask[4];
#pragma unroll
  for (int r = 0; r < 4; ++r)
    rmask[r] = maskI[(b << 10) + m0 + r] ? 1.f : 0.f;
  const float muT = muVal[b];
  const float nuT = 1.0f / (float)NQ + 1e-8f;
  float zr[4] = {0.f, 0.f, 0.f, 0.f};

  unsigned gen = 0;
  for (int it = 0; it < 100; ++it) {
    // stage w into LDS
    __syncthreads();
    for (int i = tid; i < 1024; i += 256) wS[i] = wb[i];
    __syncthreads();
    // u-phase: z for own rows
#pragma unroll
    for (int r = 0; r < 4; ++r) {
      float s = 0.f;
#pragma unroll
      for (int j = 0; j < 16; ++j) s = fmaf(e[r][j], wS[lane + (j << 6)], s);
      s = wave_reduce_sum(s);
      zr[r] = rmask[r] * (muT / fmaxf(s, 1e-35f));
    }
    // column partials for own rows
#pragma unroll
    for (int j = 0; j < 16; ++j) {
      float p = e[0][j] * zr[0] + e[1][j] * zr[1] + e[2][j] * zr[2] + e[3][j] * zr[3];
      colRed[wave][lane + (j << 6)] = p;
    }
    __syncthreads();
    for (int n = tid; n < 1024; n += 256) {
      float s = colRed[0][n] + colRed[1][n] + colRed[2][n] + colRed[3][n];
      cpB[((size_t)g << 10) + n] = s;
    }
    ++gen; wg_barrier(ctr, gen << 6);
    // v-phase: this WG computes w for its 16 columns
    {
      const int c = (g << 4) + (tid & 15);
      const int p0 = (tid >> 4) << 2;
      float s = 0.f;
#pragma unroll
      for (int p = 0; p < 4; ++p) s += cpB[((size_t)(p0 + p) << 10) + c];
      colRed[0][tid] = s;
    }
    __syncthreads();
    if (tid < 16) {
      float s = 0.f;
#pragma unroll
      for (int k2 = 0; k2 < 16; ++k2) s += colRed[0][tid + (k2 << 4)];
      wb[(g << 4) + tid] = nuT / fmaxf(s, 1e-35f);
    }
    ++gen; wg_barrier(ctr, gen << 6);
  }

  // epilogue: attn + z with final z (iter-100 u) and final w (iter-100 v)
  __syncthreads();
  for (int i = tid; i < 1024; i += 256) wS[i] = wb[i];
  __syncthreads();
#pragma unroll
  for (int r = 0; r < 4; ++r) {
    float s = 0.f;
#pragma unroll
    for (int j = 0; j < 16; ++j) {
      const float ee = e[r][j];
      const float t = ee * wS[lane + (j << 6)];
      s += (1.f + EPS_OT * __logf(ee)) * t;
    }
    s = wave_reduce_sum(s);
    if (!lane) {
      const int m = (b << 10) + m0 + r;
      z[m] = zr[r];
      attn[m] = 1048576.0f * zr[r] * s;   // M*Nq = 1024*1024
    }
  }
}

// ---------------------------------------------------------------------------
// Final: out[(n*8+b)][c] = w[b][n]*sum_m (z[b][m]*E[b][m][n])*vp[b][m][c] + bp[c]
// ---------------------------------------------------------------------------
__global__ __launch_bounds__(256)
void gemm_x(const float* __restrict__ E, const float* __restrict__ vp,
            const float* __restrict__ z, const float* __restrict__ w,
            const float* __restrict__ bp, float* __restrict__ out)
{
  __shared__ float Ts[32 * 132];
  __shared__ float Vs[32 * 132];
  const int tid = threadIdx.x;
  const int b = blockIdx.z;
  const int n0 = blockIdx.x << 7;
  const int c0 = blockIdx.y << 7;
  const int ty = tid >> 4, tx = tid & 15;
  const float* Eb = E + ((size_t)b << 20);
  const float* Vb = vp + (size_t)b * MK * CD;
  const float* zb = z + (b << 10);
  float acc[8][8];
#pragma unroll
  for (int i = 0; i < 8; ++i)
#pragma unroll
    for (int j = 0; j < 8; ++j) acc[i][j] = 0.f;

  for (int m0 = 0; m0 < MK; m0 += 32) {
#pragma unroll
    for (int t = 0; t < 4; ++t) {
      const int e = tid + (t << 8);
      const int c4 = (e & 31) << 2;
      const int k = e >> 5;
      const float zk = zb[m0 + k];
      const float4 g = *(const float4*)(Eb + ((size_t)(m0 + k) << 10) + n0 + c4);
      float4 tv;
      tv.x = g.x * zk; tv.y = g.y * zk; tv.z = g.z * zk; tv.w = g.w * zk;
      *(float4*)(Ts + k * 132 + c4) = tv;
      const float4 gv = *(const float4*)(Vb + (size_t)(m0 + k) * CD + c0 + c4);
      *(float4*)(Vs + k * 132 + c4) = gv;
    }
    __syncthreads();
#pragma unroll
    for (int k = 0; k < 32; ++k) {
      const float* ak = Ts + k * 132;
      const float* bk2 = Vs + k * 132;
      float a[8], bb[8];
      *(float4*)(a)      = *(const float4*)(ak + (ty << 2));
      *(float4*)(a + 4)  = *(const float4*)(ak + 64 + (ty << 2));
      *(float4*)(bb)     = *(const float4*)(bk2 + (tx << 2));
      *(float4*)(bb + 4) = *(const float4*)(bk2 + 64 + (tx << 2));
#pragma unroll
      for (int i = 0; i < 8; ++i)
#pragma unroll
        for (int j = 0; j < 8; ++j)
          acc[i][j] = fmaf(a[i], bb[j], acc[i][j]);
    }
    __syncthreads();
  }
#pragma unroll
  for (int i = 0; i < 8; ++i) {
    const int nrow = n0 + ((i < 4) ? ((ty << 2) + i) : (64 + (ty << 2) + i - 4));
    const float wn = w[(b << 10) + nrow];
    const size_t obase = (size_t)((nrow << 3) + b) * CD;
#pragma unroll
    for (int jh = 0; jh < 2; ++jh) {
      const int cc = c0 + (jh << 6) + (tx << 2);
      const float4 bp4 = *(const float4*)(bp + cc);
      float4 o;
      o.x = acc[i][jh * 4 + 0] * wn + bp4.x;
      o.y = acc[i][jh * 4 + 1] * wn + bp4.y;
      o.z = acc[i][jh * 4 + 2] * wn + bp4.z;
      o.w = acc[i][jh * 4 + 3] * wn + bp4.w;
      *(float4*)(out + obase + cc) = o;
    }
  }
}

// ---------------------------------------------------------------------------
extern "C" void kernel_launch(void* const* d_in, const int* in_sizes, int n_in,
                              void* d_out, int out_size, void* d_ws, size_t ws_size,
                              hipStream_t stream)
{
  const float* xq = (const float*)d_in[0];
  const float* xk = (const float*)d_in[1];
  const float* xv = (const float*)d_in[2];
  const void*  maskRaw = d_in[3];
  const float* Wq = (const float*)d_in[4];
  const float* bq = (const float*)d_in[5];
  const float* Wk = (const float*)d_in[6];
  const float* bk = (const float*)d_in[7];
  const float* Wv = (const float*)d_in[8];
  // bv = d_in[9]
  const float* bv = (const float*)d_in[9];
  const float* Wp = (const float*)d_in[10];
  const float* bp = (const float*)d_in[11];

  float* out  = (float*)d_out;
  float* attn = out + (size_t)NQ * B_DIM * CD;

  float* qb  = (float*)d_ws;                      // [B][Nq][C]
  float* kb  = qb + (size_t)B_DIM * NQ * CD;      // [B][M][C]
  float* vpb = kb + (size_t)B_DIM * MK * CD;      // [B][M][C]  (v @ Wp.T)
  float* E   = vpb + (size_t)B_DIM * MK * CD;     // [B][M][Nq]
  float* z   = E + (size_t)B_DIM * MK * NQ;       // [B][M]
  float* w   = z + B_DIM * MK;                    // [B][Nq]
  int*   maskI = (int*)(w + B_DIM * NQ);          // [B][M]
  float* muVal = (float*)(maskI + B_DIM * MK);    // [B]
  unsigned* barCtr = (unsigned*)(muVal + B_DIM);  // [8*32]
  // overlays (regions dead at time of use):
  float* A    = E;                                // 640*640, dead before sim writes E
  float* bvp  = E + CD * CD;                      // 640
  float* colPart = qb;                            // [B][64][1024], qb dead after sim

  k_combineA<<<dim3(10, 10), 256, 0, stream>>>(Wp, Wv, A);
  k_bvp<<<160, 256, 0, stream>>>(Wp, bv, bvp);
  k_setup<<<1, 1024, 0, stream>>>(maskRaw, maskI, muVal, w, barCtr);

  gemm_proj3<<<dim3(64, 5, 3), 256, 0, stream>>>(xq, xk, xv, Wq, bq, Wk, bk,
                                                 A, bvp, qb, kb, vpb);
  k_l2norm<<<4096, 256, 0, stream>>>(qb);   // qb and kb are contiguous: 16384 rows

  gemm_sim<<<dim3(8, 8, 8), 256, 0, stream>>>(kb, qb, E);

  {
    void* args[] = {(void*)&E, (void*)&maskI, (void*)&muVal, (void*)&w,
                    (void*)&z, (void*)&attn, (void*)&colPart, (void*)&barCtr};
    hipLaunchCooperativeKernel((void*)k_sinkhorn, dim3(512), dim3(256),
                               args, 0, stream);
  }

  gemm_x<<<dim3(8, 5, 8), 256, 0, stream>>>(E, vpb, z, w, bp, out);
}

// Round 3
// 2740.187 us; speedup vs baseline: 2.1549x; 2.1026x over previous
//
#include <hip/hip_runtime.h>
#include <cstdint>
#include <cstddef>

#define B_DIM 8
#define NQ    1024
#define MK    1024
#define CD    640
#define INV_EPS 20.0f
#define EPS_OT  0.05f

static __device__ __forceinline__ float wave_reduce_sum(float s) {
#pragma unroll
  for (int off = 32; off; off >>= 1) s += __shfl_xor(s, off, 64);
  return s;
}

// Device-scope (cross-XCD coherent) relaxed accesses: emit sc1 per-access ops,
// no L2 writeback/invalidate storms.
static __device__ __forceinline__ void g_store(float* p, float v) {
  __hip_atomic_store(p, v, __ATOMIC_RELAXED, __HIP_MEMORY_SCOPE_AGENT);
}
static __device__ __forceinline__ float g_load(const float* p) {
  return __hip_atomic_load((float*)p, __ATOMIC_RELAXED, __HIP_MEMORY_SCOPE_AGENT);
}

// ---------------------------------------------------------------------------
// Setup: detect mask dtype, build maskI, per-batch mu, w=1, zero barrier ctrs
// ---------------------------------------------------------------------------
__global__ void k_setup(const void* __restrict__ maskRaw, int* __restrict__ maskI,
                        float* __restrict__ muVal, float* __restrict__ w,
                        unsigned* __restrict__ barCtr)
{
  __shared__ int s_flag;
  __shared__ int s_cnt[B_DIM];
  const int tid = threadIdx.x;
  if (tid == 0) s_flag = 0;
  if (tid < B_DIM) s_cnt[tid] = 0;
  if (tid < 256) barCtr[tid] = 0u;
  __syncthreads();

  const unsigned char* mb = (const unsigned char*)maskRaw;
  int local = 0;
  for (int i = tid; i < B_DIM * MK; i += 1024)
    if ((i & 3) && mb[i]) local = 1;
  if (local) atomicOr(&s_flag, 1);
  __syncthreads();

  const int isByte = s_flag;
  const int* mi32 = (const int*)maskRaw;
  for (int i = tid; i < B_DIM * MK; i += 1024) {
    int v = isByte ? (int)mb[i] : mi32[i];
    v = v ? 1 : 0;
    maskI[i] = v;
    if (v) atomicAdd(&s_cnt[i >> 10], 1);
  }
  for (int i = tid; i < B_DIM * NQ; i += 1024) w[i] = 1.0f;
  __syncthreads();
  if (tid < B_DIM) {
    float c = (float)s_cnt[tid];
    muVal[tid] = (c > 0.f ? 1.0f / c : 1.0f / (float)MK) + 1e-8f;
  }
}

// ---------------------------------------------------------------------------
// A = Wp @ Wv  (A[c][k] = sum_j Wp[c][j]*Wv[j][k]), 640x640. 64x64 tiles.
// ---------------------------------------------------------------------------
__global__ __launch_bounds__(256)
void k_combineA(const float* __restrict__ Wp, const float* __restrict__ Wv,
                float* __restrict__ A)
{
  __shared__ float Ps[32][68];
  __shared__ float Vs[32][68];
  const int tid = threadIdx.x;
  const int c0 = blockIdx.x << 6, k0 = blockIdx.y << 6;
  const int ty = tid >> 4, tx = tid & 15;
  float acc[4][4];
#pragma unroll
  for (int i = 0; i < 4; ++i)
#pragma unroll
    for (int j = 0; j < 4; ++j) acc[i][j] = 0.f;

  for (int j0 = 0; j0 < CD; j0 += 32) {
    {
      const int c = tid >> 2, j4 = (tid & 3) << 3;
      const float* p = Wp + (size_t)(c0 + c) * CD + j0 + j4;
      float4 u0 = *(const float4*)p, u1 = *(const float4*)(p + 4);
      Ps[j4 + 0][c] = u0.x; Ps[j4 + 1][c] = u0.y; Ps[j4 + 2][c] = u0.z; Ps[j4 + 3][c] = u0.w;
      Ps[j4 + 4][c] = u1.x; Ps[j4 + 5][c] = u1.y; Ps[j4 + 6][c] = u1.z; Ps[j4 + 7][c] = u1.w;
    }
    {
      const int j = tid >> 3, k4 = (tid & 7) << 3;
      const float* p = Wv + (size_t)(j0 + j) * CD + k0 + k4;
      float4 u0 = *(const float4*)p, u1 = *(const float4*)(p + 4);
      *(float4*)&Vs[j][k4] = u0; *(float4*)&Vs[j][k4 + 4] = u1;
    }
    __syncthreads();
#pragma unroll
    for (int j = 0; j < 32; ++j) {
      float a[4], b[4];
      *(float4*)a = *(const float4*)&Ps[j][ty << 2];
      *(float4*)b = *(const float4*)&Vs[j][tx << 2];
#pragma unroll
      for (int i = 0; i < 4; ++i)
#pragma unroll
        for (int jj = 0; jj < 4; ++jj)
          acc[i][jj] = fmaf(a[i], b[jj], acc[i][jj]);
    }
    __syncthreads();
  }
#pragma unroll
  for (int i = 0; i < 4; ++i) {
    float4 o; o.x = acc[i][0]; o.y = acc[i][1]; o.z = acc[i][2]; o.w = acc[i][3];
    *(float4*)(A + (size_t)(c0 + (ty << 2) + i) * CD + k0 + (tx << 2)) = o;
  }
}

// bvp[c] = sum_j Wp[c][j]*bv[j]
__global__ __launch_bounds__(256)
void k_bvp(const float* __restrict__ Wp, const float* __restrict__ bv,
           float* __restrict__ bvp)
{
  const int c = (blockIdx.x << 2) + (threadIdx.x >> 6);
  const int lane = threadIdx.x & 63;
  float s = 0.f;
  for (int j = lane; j < CD; j += 64) s = fmaf(Wp[(size_t)c * CD + j], bv[j], s);
  s = wave_reduce_sum(s);
  if (!lane) bvp[c] = s;
}

// ---------------------------------------------------------------------------
// Merged projections (q/k/v-combined), 128x128 tiles, grid (64,5,3).
// ---------------------------------------------------------------------------
__global__ __launch_bounds__(256)
void gemm_proj3(const float* __restrict__ xq, const float* __restrict__ xk,
                const float* __restrict__ xv,
                const float* __restrict__ Wq, const float* __restrict__ bq,
                const float* __restrict__ Wk, const float* __restrict__ bk,
                const float* __restrict__ Wvp, const float* __restrict__ bvp,
                float* __restrict__ qb, float* __restrict__ kb,
                float* __restrict__ vpb)
{
  __shared__ float As[32 * 132];
  __shared__ float Bs[32 * 132];
  const int mode = blockIdx.z;
  const float* X    = (mode == 0) ? xq  : ((mode == 1) ? xk : xv);
  const float* W    = (mode == 0) ? Wq  : ((mode == 1) ? Wk : Wvp);
  const float* bias = (mode == 0) ? bq  : ((mode == 1) ? bk : bvp);
  float* out        = (mode == 0) ? qb  : ((mode == 1) ? kb : vpb);

  const int tid = threadIdx.x;
  const int row0 = blockIdx.x << 7;
  const int col0 = blockIdx.y << 7;
  const int ty = tid >> 4, tx = tid & 15;
  float acc[8][8];
#pragma unroll
  for (int i = 0; i < 8; ++i)
#pragma unroll
    for (int j = 0; j < 8; ++j) acc[i][j] = 0.f;

  for (int k0 = 0; k0 < CD; k0 += 32) {
    const float* Ap = X + (size_t)row0 * CD + k0;
    const float* Wp2 = W + (size_t)col0 * CD + k0;
#pragma unroll
    for (int t = 0; t < 4; ++t) {
      const int e = tid + (t << 8);
      const int r = e >> 3;
      const int kq = (e & 7) << 2;
      const float4 ga = *(const float4*)(Ap + (size_t)r * CD + kq);
      As[(kq + 0) * 132 + r] = ga.x;
      As[(kq + 1) * 132 + r] = ga.y;
      As[(kq + 2) * 132 + r] = ga.z;
      As[(kq + 3) * 132 + r] = ga.w;
      const float4 gb = *(const float4*)(Wp2 + (size_t)r * CD + kq);
      Bs[(kq + 0) * 132 + r] = gb.x;
      Bs[(kq + 1) * 132 + r] = gb.y;
      Bs[(kq + 2) * 132 + r] = gb.z;
      Bs[(kq + 3) * 132 + r] = gb.w;
    }
    __syncthreads();
#pragma unroll
    for (int k = 0; k < 32; ++k) {
      const float* ak = As + k * 132;
      const float* bk2 = Bs + k * 132;
      float a[8], b[8];
      *(float4*)(a)     = *(const float4*)(ak + (ty << 2));
      *(float4*)(a + 4) = *(const float4*)(ak + 64 + (ty << 2));
      *(float4*)(b)     = *(const float4*)(bk2 + (tx << 2));
      *(float4*)(b + 4) = *(const float4*)(bk2 + 64 + (tx << 2));
#pragma unroll
      for (int i = 0; i < 8; ++i)
#pragma unroll
        for (int j = 0; j < 8; ++j)
          acc[i][j] = fmaf(a[i], b[j], acc[i][j]);
    }
    __syncthreads();
  }
#pragma unroll
  for (int i = 0; i < 8; ++i) {
    const int rr = row0 + ((i < 4) ? ((ty << 2) + i) : (64 + (ty << 2) + i - 4));
    size_t orow;
    if (mode == 0) orow = (size_t)(rr & 7) * NQ + (rr >> 3);
    else           orow = (size_t)rr;
#pragma unroll
    for (int jh = 0; jh < 2; ++jh) {
      const int cc = col0 + (jh << 6) + (tx << 2);
      const float4 bv4 = *(const float4*)(bias + cc);
      float4 o;
      o.x = acc[i][jh * 4 + 0] + bv4.x;
      o.y = acc[i][jh * 4 + 1] + bv4.y;
      o.z = acc[i][jh * 4 + 2] + bv4.z;
      o.w = acc[i][jh * 4 + 3] + bv4.w;
      *(float4*)(out + orow * CD + cc) = o;
    }
  }
}

// ---------------------------------------------------------------------------
// l2norm over rows of 640 (one wave per row)
// ---------------------------------------------------------------------------
__global__ __launch_bounds__(256)
void k_l2norm(float* __restrict__ X)
{
  const int row = (blockIdx.x << 2) + (threadIdx.x >> 6);
  const int lane = threadIdx.x & 63;
  float2* p2 = (float2*)(X + (size_t)row * CD);
  float ss = 0.f;
#pragma unroll
  for (int i = 0; i < 5; ++i) {
    float2 v = p2[lane + (i << 6)];
    ss = fmaf(v.x, v.x, fmaf(v.y, v.y, ss));
  }
  ss = wave_reduce_sum(ss);
  const float inv = 1.0f / fmaxf(sqrtf(ss), 1e-12f);
#pragma unroll
  for (int i = 0; i < 5; ++i) {
    float2 v = p2[lane + (i << 6)];
    v.x *= inv; v.y *= inv;
    p2[lane + (i << 6)] = v;
  }
}

// ---------------------------------------------------------------------------
// sim GEMM (NT, batched): E[b][m][n] = exp((k[b][m]·q[b][n] - 1) * 20)
// ---------------------------------------------------------------------------
__global__ __launch_bounds__(256)
void gemm_sim(const float* __restrict__ kb, const float* __restrict__ qb,
              float* __restrict__ E)
{
  __shared__ float As[32 * 132];
  __shared__ float Bs[32 * 132];
  const int tid = threadIdx.x;
  const int b = blockIdx.z;
  const int row0 = blockIdx.x << 7;
  const int col0 = blockIdx.y << 7;
  const int ty = tid >> 4, tx = tid & 15;
  const float* A = kb + (size_t)b * MK * CD;
  const float* Bq = qb + (size_t)b * NQ * CD;
  float acc[8][8];
#pragma unroll
  for (int i = 0; i < 8; ++i)
#pragma unroll
    for (int j = 0; j < 8; ++j) acc[i][j] = 0.f;

  for (int k0 = 0; k0 < CD; k0 += 32) {
    const float* Ap = A + (size_t)row0 * CD + k0;
    const float* Bp = Bq + (size_t)col0 * CD + k0;
#pragma unroll
    for (int t = 0; t < 4; ++t) {
      const int e = tid + (t << 8);
      const int r = e >> 3;
      const int kq = (e & 7) << 2;
      const float4 ga = *(const float4*)(Ap + (size_t)r * CD + kq);
      As[(kq + 0) * 132 + r] = ga.x;
      As[(kq + 1) * 132 + r] = ga.y;
      As[(kq + 2) * 132 + r] = ga.z;
      As[(kq + 3) * 132 + r] = ga.w;
      const float4 gb = *(const float4*)(Bp + (size_t)r * CD + kq);
      Bs[(kq + 0) * 132 + r] = gb.x;
      Bs[(kq + 1) * 132 + r] = gb.y;
      Bs[(kq + 2) * 132 + r] = gb.z;
      Bs[(kq + 3) * 132 + r] = gb.w;
    }
    __syncthreads();
#pragma unroll
    for (int k = 0; k < 32; ++k) {
      const float* ak = As + k * 132;
      const float* bk2 = Bs + k * 132;
      float a[8], bb[8];
      *(float4*)(a)      = *(const float4*)(ak + (ty << 2));
      *(float4*)(a + 4)  = *(const float4*)(ak + 64 + (ty << 2));
      *(float4*)(bb)     = *(const float4*)(bk2 + (tx << 2));
      *(float4*)(bb + 4) = *(const float4*)(bk2 + 64 + (tx << 2));
#pragma unroll
      for (int i = 0; i < 8; ++i)
#pragma unroll
        for (int j = 0; j < 8; ++j)
          acc[i][j] = fmaf(a[i], bb[j], acc[i][j]);
    }
    __syncthreads();
  }
#pragma unroll
  for (int i = 0; i < 8; ++i) {
    const int rr = row0 + ((i < 4) ? ((ty << 2) + i) : (64 + (ty << 2) + i - 4));
    const size_t ebase = ((size_t)b * MK + rr) * NQ;
#pragma unroll
    for (int jh = 0; jh < 2; ++jh) {
      const int cc = col0 + (jh << 6) + (tx << 2);
      float4 o;
      o.x = __expf((acc[i][jh * 4 + 0] - 1.f) * INV_EPS);
      o.y = __expf((acc[i][jh * 4 + 1] - 1.f) * INV_EPS);
      o.z = __expf((acc[i][jh * 4 + 2] - 1.f) * INV_EPS);
      o.w = __expf((acc[i][jh * 4 + 3] - 1.f) * INV_EPS);
      *(float4*)(E + ebase + cc) = o;
    }
  }
}

// ---------------------------------------------------------------------------
// Per-batch spin barrier: release-RMW arrival (agent scope), RELAXED polling
// (no per-poll cache invalidates), workgroup-acquire fence on exit. All
// cross-WG payload moves via sc1 relaxed atomics, so no L2 flush is needed
// for data visibility.
// ---------------------------------------------------------------------------
__device__ __forceinline__ void wg_barrier(unsigned* ctr, unsigned target) {
  __syncthreads();   // drains each wave's vmcnt -> payload stores complete
  if (threadIdx.x == 0) {
    __hip_atomic_fetch_add(ctr, 1u, __ATOMIC_RELEASE, __HIP_MEMORY_SCOPE_AGENT);
    while (__hip_atomic_load(ctr, __ATOMIC_RELAXED, __HIP_MEMORY_SCOPE_AGENT) < target)
      __builtin_amdgcn_s_sleep(4);
    __builtin_amdgcn_fence(__ATOMIC_ACQUIRE, "workgroup");  // compiler order + L0 inv only
  }
  __syncthreads();
}

__global__ __launch_bounds__(256)
void k_sinkhorn(const float* __restrict__ E, const int* __restrict__ maskI,
                const float* __restrict__ muVal, float* __restrict__ w,
                float* __restrict__ z, float* __restrict__ attn,
                float* __restrict__ colPart, unsigned* __restrict__ barCtr)
{
  // XCD-affinity swizzle: round-robin dispatch puts blockIdx%8 on one XCD, so
  // batch b's 64 WGs co-locate (perf heuristic only; correctness from sc1 ops)
  const int b = blockIdx.x & 7;
  const int g = blockIdx.x >> 3;
  const int tid = threadIdx.x;
  const int wave = tid >> 6, lane = tid & 63;
  const int m0 = (g << 4) + (wave << 2);
  const float* Eb = E + ((size_t)b << 20);
  float* wb = w + (b << 10);
  float* cpB = colPart + ((size_t)b << 16);
  unsigned* ctr = barCtr + b * 32;

  __shared__ float wS[1024];
  __shared__ float colRed[4][1024];

  float e[4][16];
#pragma unroll
  for (int r = 0; r < 4; ++r) {
    const float* row = Eb + ((size_t)(m0 + r) << 10) + lane;
#pragma unroll
    for (int j = 0; j < 16; ++j) e[r][j] = row[j << 6];
  }
  float rmask[4];
#pragma unroll
  for (int r = 0; r < 4; ++r)
    rmask[r] = maskI[(b << 10) + m0 + r] ? 1.f : 0.f;
  const float muT = muVal[b];
  const float nuT = 1.0f / (float)NQ + 1e-8f;
  float zr[4] = {0.f, 0.f, 0.f, 0.f};

  // w starts as 1.0 everywhere (k_setup)
#pragma unroll
  for (int i0 = 0; i0 < 4; ++i0) wS[tid + (i0 << 8)] = 1.0f;
  __syncthreads();

  unsigned gen = 0;
  for (int it = 0; it < 100; ++it) {
    // u-phase: z for own rows (w already staged in wS)
#pragma unroll
    for (int r = 0; r < 4; ++r) {
      float s = 0.f;
#pragma unroll
      for (int j = 0; j < 16; ++j) s = fmaf(e[r][j], wS[lane + (j << 6)], s);
      s = wave_reduce_sum(s);
      zr[r] = rmask[r] * (muT / fmaxf(s, 1e-35f));
    }
    // column partials for own rows
#pragma unroll
    for (int j = 0; j < 16; ++j) {
      float p = e[0][j] * zr[0] + e[1][j] * zr[1] + e[2][j] * zr[2] + e[3][j] * zr[3];
      colRed[wave][lane + (j << 6)] = p;
    }
    __syncthreads();
    for (int n = tid; n < 1024; n += 256) {
      float s = colRed[0][n] + colRed[1][n] + colRed[2][n] + colRed[3][n];
      g_store(cpB + ((size_t)g << 10) + n, s);
    }
    ++gen; wg_barrier(ctr, gen << 6);
    // v-phase: this WG computes w for its 16 columns from all 64 partials
    {
      const int c = (g << 4) + (tid & 15);
      const int p0 = (tid >> 4) << 2;
      float s = 0.f;
#pragma unroll
      for (int p = 0; p < 4; ++p) s += g_load(cpB + ((size_t)(p0 + p) << 10) + c);
      colRed[0][tid] = s;
    }
    __syncthreads();
    if (tid < 16) {
      float s = 0.f;
#pragma unroll
      for (int k2 = 0; k2 < 16; ++k2) s += colRed[0][tid + (k2 << 4)];
      g_store(wb + (g << 4) + tid, nuT / fmaxf(s, 1e-35f));
    }
    ++gen; wg_barrier(ctr, gen << 6);
    // stage fresh w into LDS for next u-phase / epilogue
    for (int i = tid; i < 1024; i += 256) wS[i] = g_load(wb + i);
    __syncthreads();
  }

  // epilogue: attn + z with final z and final w (already in wS)
#pragma unroll
  for (int r = 0; r < 4; ++r) {
    float s = 0.f;
#pragma unroll
    for (int j = 0; j < 16; ++j) {
      const float ee = e[r][j];
      const float t = ee * wS[lane + (j << 6)];
      s += (1.f + EPS_OT * __logf(ee)) * t;
    }
    s = wave_reduce_sum(s);
    if (!lane) {
      const int m = (b << 10) + m0 + r;
      z[m] = zr[r];
      attn[m] = 1048576.0f * zr[r] * s;   // M*Nq
    }
  }
}

// ---------------------------------------------------------------------------
// Final: out[(n*8+b)][c] = w[b][n]*sum_m (z[b][m]*E[b][m][n])*vp[b][m][c] + bp[c]
// ---------------------------------------------------------------------------
__global__ __launch_bounds__(256)
void gemm_x(const float* __restrict__ E, const float* __restrict__ vp,
            const float* __restrict__ z, const float* __restrict__ w,
            const float* __restrict__ bp, float* __restrict__ out)
{
  __shared__ float Ts[32 * 132];
  __shared__ float Vs[32 * 132];
  const int tid = threadIdx.x;
  const int b = blockIdx.z;
  const int n0 = blockIdx.x << 7;
  const int c0 = blockIdx.y << 7;
  const int ty = tid >> 4, tx = tid & 15;
  const float* Eb = E + ((size_t)b << 20);
  const float* Vb = vp + (size_t)b * MK * CD;
  const float* zb = z + (b << 10);
  float acc[8][8];
#pragma unroll
  for (int i = 0; i < 8; ++i)
#pragma unroll
    for (int j = 0; j < 8; ++j) acc[i][j] = 0.f;

  for (int m0 = 0; m0 < MK; m0 += 32) {
#pragma unroll
    for (int t = 0; t < 4; ++t) {
      const int e = tid + (t << 8);
      const int c4 = (e & 31) << 2;
      const int k = e >> 5;
      const float zk = zb[m0 + k];
      const float4 g = *(const float4*)(Eb + ((size_t)(m0 + k) << 10) + n0 + c4);
      float4 tv;
      tv.x = g.x * zk; tv.y = g.y * zk; tv.z = g.z * zk; tv.w = g.w * zk;
      *(float4*)(Ts + k * 132 + c4) = tv;
      const float4 gv = *(const float4*)(Vb + (size_t)(m0 + k) * CD + c0 + c4);
      *(float4*)(Vs + k * 132 + c4) = gv;
    }
    __syncthreads();
#pragma unroll
    for (int k = 0; k < 32; ++k) {
      const float* ak = Ts + k * 132;
      const float* bk2 = Vs + k * 132;
      float a[8], bb[8];
      *(float4*)(a)      = *(const float4*)(ak + (ty << 2));
      *(float4*)(a + 4)  = *(const float4*)(ak + 64 + (ty << 2));
      *(float4*)(bb)     = *(const float4*)(bk2 + (tx << 2));
      *(float4*)(bb + 4) = *(const float4*)(bk2 + 64 + (tx << 2));
#pragma unroll
      for (int i = 0; i < 8; ++i)
#pragma unroll
        for (int j = 0; j < 8; ++j)
          acc[i][j] = fmaf(a[i], bb[j], acc[i][j]);
    }
    __syncthreads();
  }
#pragma unroll
  for (int i = 0; i < 8; ++i) {
    const int nrow = n0 + ((i < 4) ? ((ty << 2) + i) : (64 + (ty << 2) + i - 4));
    const float wn = w[(b << 10) + nrow];
    const size_t obase = (size_t)((nrow << 3) + b) * CD;
#pragma unroll
    for (int jh = 0; jh < 2; ++jh) {
      const int cc = c0 + (jh << 6) + (tx << 2);
      const float4 bp4 = *(const float4*)(bp + cc);
      float4 o;
      o.x = acc[i][jh * 4 + 0] * wn + bp4.x;
      o.y = acc[i][jh * 4 + 1] * wn + bp4.y;
      o.z = acc[i][jh * 4 + 2] * wn + bp4.z;
      o.w = acc[i][jh * 4 + 3] * wn + bp4.w;
      *(float4*)(out + obase + cc) = o;
    }
  }
}

// ---------------------------------------------------------------------------
extern "C" void kernel_launch(void* const* d_in, const int* in_sizes, int n_in,
                              void* d_out, int out_size, void* d_ws, size_t ws_size,
                              hipStream_t stream)
{
  const float* xq = (const float*)d_in[0];
  const float* xk = (const float*)d_in[1];
  const float* xv = (const float*)d_in[2];
  const void*  maskRaw = d_in[3];
  const float* Wq = (const float*)d_in[4];
  const float* bq = (const float*)d_in[5];
  const float* Wk = (const float*)d_in[6];
  const float* bk = (const float*)d_in[7];
  const float* Wv = (const float*)d_in[8];
  const float* bv = (const float*)d_in[9];
  const float* Wp = (const float*)d_in[10];
  const float* bp = (const float*)d_in[11];

  float* out  = (float*)d_out;
  float* attn = out + (size_t)NQ * B_DIM * CD;

  float* qb  = (float*)d_ws;                      // [B][Nq][C]
  float* kb  = qb + (size_t)B_DIM * NQ * CD;      // [B][M][C]
  float* vpb = kb + (size_t)B_DIM * MK * CD;      // [B][M][C]  (v @ Wp.T)
  float* E   = vpb + (size_t)B_DIM * MK * CD;     // [B][M][Nq]
  float* z   = E + (size_t)B_DIM * MK * NQ;       // [B][M]
  float* w   = z + B_DIM * MK;                    // [B][Nq]
  int*   maskI = (int*)(w + B_DIM * NQ);          // [B][M]
  float* muVal = (float*)(maskI + B_DIM * MK);    // [B]
  unsigned* barCtr = (unsigned*)(muVal + B_DIM);  // [8*32]
  // overlays (dead regions at time of use):
  float* A    = E;                                // 640*640, dead before sim
  float* bvp  = E + CD * CD;                      // 640
  float* colPart = qb;                            // [B][64][1024], qb dead after sim

  k_combineA<<<dim3(10, 10), 256, 0, stream>>>(Wp, Wv, A);
  k_bvp<<<160, 256, 0, stream>>>(Wp, bv, bvp);
  k_setup<<<1, 1024, 0, stream>>>(maskRaw, maskI, muVal, w, barCtr);

  gemm_proj3<<<dim3(64, 5, 3), 256, 0, stream>>>(xq, xk, xv, Wq, bq, Wk, bk,
                                                 A, bvp, qb, kb, vpb);
  k_l2norm<<<4096, 256, 0, stream>>>(qb);   // qb,kb contiguous: 16384 rows

  gemm_sim<<<dim3(8, 8, 8), 256, 0, stream>>>(kb, qb, E);

  {
    void* args[] = {(void*)&E, (void*)&maskI, (void*)&muVal, (void*)&w,
                    (void*)&z, (void*)&attn, (void*)&colPart, (void*)&barCtr};
    hipLaunchCooperativeKernel((void*)k_sinkhorn, dim3(512), dim3(256),
                               args, 0, stream);
  }

  gemm_x<<<dim3(8, 5, 8), 256, 0, stream>>>(E, vpb, z, w, bp, out);
}

// Round 4
// 1286.662 us; speedup vs baseline: 4.5893x; 2.1297x over previous
//
#include <hip/hip_runtime.h>
#include <cstdint>
#include <cstddef>

#define B_DIM 8
#define NQ    1024
#define MK    1024
#define CD    640
#define INV_EPS 20.0f
#define EPS_OT  0.05f

static __device__ __forceinline__ float wave_reduce_sum(float s) {
#pragma unroll
  for (int off = 32; off; off >>= 1) s += __shfl_xor(s, off, 64);
  return s;
}

// Device-scope (cross-XCD coherent) relaxed accesses: per-access sc1 ops,
// no L2 writeback/invalidate storms.
static __device__ __forceinline__ void g_store(float* p, float v) {
  __hip_atomic_store(p, v, __ATOMIC_RELAXED, __HIP_MEMORY_SCOPE_AGENT);
}
static __device__ __forceinline__ float g_load(const float* p) {
  return __hip_atomic_load((float*)p, __ATOMIC_RELAXED, __HIP_MEMORY_SCOPE_AGENT);
}

// ---------------------------------------------------------------------------
// Setup: detect mask dtype, build maskI, per-batch mu, w=1, zero barrier ctrs
// ---------------------------------------------------------------------------
__global__ void k_setup(const void* __restrict__ maskRaw, int* __restrict__ maskI,
                        float* __restrict__ muVal, float* __restrict__ w,
                        unsigned* __restrict__ barCtr)
{
  __shared__ int s_flag;
  __shared__ int s_cnt[B_DIM];
  const int tid = threadIdx.x;
  if (tid == 0) s_flag = 0;
  if (tid < B_DIM) s_cnt[tid] = 0;
  if (tid < 256) barCtr[tid] = 0u;
  __syncthreads();

  const unsigned char* mb = (const unsigned char*)maskRaw;
  int local = 0;
  for (int i = tid; i < B_DIM * MK; i += 1024)
    if ((i & 3) && mb[i]) local = 1;
  if (local) atomicOr(&s_flag, 1);
  __syncthreads();

  const int isByte = s_flag;
  const int* mi32 = (const int*)maskRaw;
  for (int i = tid; i < B_DIM * MK; i += 1024) {
    int v = isByte ? (int)mb[i] : mi32[i];
    v = v ? 1 : 0;
    maskI[i] = v;
    if (v) atomicAdd(&s_cnt[i >> 10], 1);
  }
  for (int i = tid; i < B_DIM * NQ; i += 1024) w[i] = 1.0f;
  __syncthreads();
  if (tid < B_DIM) {
    float c = (float)s_cnt[tid];
    muVal[tid] = (c > 0.f ? 1.0f / c : 1.0f / (float)MK) + 1e-8f;
  }
}

// ---------------------------------------------------------------------------
// A = Wp @ Wv  (A[c][k] = sum_j Wp[c][j]*Wv[j][k]), 640x640. 64x64 tiles.
// ---------------------------------------------------------------------------
__global__ __launch_bounds__(256)
void k_combineA(const float* __restrict__ Wp, const float* __restrict__ Wv,
                float* __restrict__ A)
{
  __shared__ float Ps[32][68];
  __shared__ float Vs[32][68];
  const int tid = threadIdx.x;
  const int c0 = blockIdx.x << 6, k0 = blockIdx.y << 6;
  const int ty = tid >> 4, tx = tid & 15;
  float acc[4][4];
#pragma unroll
  for (int i = 0; i < 4; ++i)
#pragma unroll
    for (int j = 0; j < 4; ++j) acc[i][j] = 0.f;

  for (int j0 = 0; j0 < CD; j0 += 32) {
    {
      const int c = tid >> 2, j4 = (tid & 3) << 3;
      const float* p = Wp + (size_t)(c0 + c) * CD + j0 + j4;
      float4 u0 = *(const float4*)p, u1 = *(const float4*)(p + 4);
      Ps[j4 + 0][c] = u0.x; Ps[j4 + 1][c] = u0.y; Ps[j4 + 2][c] = u0.z; Ps[j4 + 3][c] = u0.w;
      Ps[j4 + 4][c] = u1.x; Ps[j4 + 5][c] = u1.y; Ps[j4 + 6][c] = u1.z; Ps[j4 + 7][c] = u1.w;
    }
    {
      const int j = tid >> 3, k4 = (tid & 7) << 3;
      const float* p = Wv + (size_t)(j0 + j) * CD + k0 + k4;
      float4 u0 = *(const float4*)p, u1 = *(const float4*)(p + 4);
      *(float4*)&Vs[j][k4] = u0; *(float4*)&Vs[j][k4 + 4] = u1;
    }
    __syncthreads();
#pragma unroll
    for (int j = 0; j < 32; ++j) {
      float a[4], b[4];
      *(float4*)a = *(const float4*)&Ps[j][ty << 2];
      *(float4*)b = *(const float4*)&Vs[j][tx << 2];
#pragma unroll
      for (int i = 0; i < 4; ++i)
#pragma unroll
        for (int jj = 0; jj < 4; ++jj)
          acc[i][jj] = fmaf(a[i], b[jj], acc[i][jj]);
    }
    __syncthreads();
  }
#pragma unroll
  for (int i = 0; i < 4; ++i) {
    float4 o; o.x = acc[i][0]; o.y = acc[i][1]; o.z = acc[i][2]; o.w = acc[i][3];
    *(float4*)(A + (size_t)(c0 + (ty << 2) + i) * CD + k0 + (tx << 2)) = o;
  }
}

// bvp[c] = sum_j Wp[c][j]*bv[j]
__global__ __launch_bounds__(256)
void k_bvp(const float* __restrict__ Wp, const float* __restrict__ bv,
           float* __restrict__ bvp)
{
  const int c = (blockIdx.x << 2) + (threadIdx.x >> 6);
  const int lane = threadIdx.x & 63;
  float s = 0.f;
  for (int j = lane; j < CD; j += 64) s = fmaf(Wp[(size_t)c * CD + j], bv[j], s);
  s = wave_reduce_sum(s);
  if (!lane) bvp[c] = s;
}

// ---------------------------------------------------------------------------
// Merged projections (q/k/v-combined), 128x128 tiles, grid (64,5,3).
// ---------------------------------------------------------------------------
__global__ __launch_bounds__(256)
void gemm_proj3(const float* __restrict__ xq, const float* __restrict__ xk,
                const float* __restrict__ xv,
                const float* __restrict__ Wq, const float* __restrict__ bq,
                const float* __restrict__ Wk, const float* __restrict__ bk,
                const float* __restrict__ Wvp, const float* __restrict__ bvp,
                float* __restrict__ qb, float* __restrict__ kb,
                float* __restrict__ vpb)
{
  __shared__ float As[32 * 132];
  __shared__ float Bs[32 * 132];
  const int mode = blockIdx.z;
  const float* X    = (mode == 0) ? xq  : ((mode == 1) ? xk : xv);
  const float* W    = (mode == 0) ? Wq  : ((mode == 1) ? Wk : Wvp);
  const float* bias = (mode == 0) ? bq  : ((mode == 1) ? bk : bvp);
  float* out        = (mode == 0) ? qb  : ((mode == 1) ? kb : vpb);

  const int tid = threadIdx.x;
  const int row0 = blockIdx.x << 7;
  const int col0 = blockIdx.y << 7;
  const int ty = tid >> 4, tx = tid & 15;
  float acc[8][8];
#pragma unroll
  for (int i = 0; i < 8; ++i)
#pragma unroll
    for (int j = 0; j < 8; ++j) acc[i][j] = 0.f;

  for (int k0 = 0; k0 < CD; k0 += 32) {
    const float* Ap = X + (size_t)row0 * CD + k0;
    const float* Wp2 = W + (size_t)col0 * CD + k0;
#pragma unroll
    for (int t = 0; t < 4; ++t) {
      const int e = tid + (t << 8);
      const int r = e >> 3;
      const int kq = (e & 7) << 2;
      const float4 ga = *(const float4*)(Ap + (size_t)r * CD + kq);
      As[(kq + 0) * 132 + r] = ga.x;
      As[(kq + 1) * 132 + r] = ga.y;
      As[(kq + 2) * 132 + r] = ga.z;
      As[(kq + 3) * 132 + r] = ga.w;
      const float4 gb = *(const float4*)(Wp2 + (size_t)r * CD + kq);
      Bs[(kq + 0) * 132 + r] = gb.x;
      Bs[(kq + 1) * 132 + r] = gb.y;
      Bs[(kq + 2) * 132 + r] = gb.z;
      Bs[(kq + 3) * 132 + r] = gb.w;
    }
    __syncthreads();
#pragma unroll
    for (int k = 0; k < 32; ++k) {
      const float* ak = As + k * 132;
      const float* bk2 = Bs + k * 132;
      float a[8], b[8];
      *(float4*)(a)     = *(const float4*)(ak + (ty << 2));
      *(float4*)(a + 4) = *(const float4*)(ak + 64 + (ty << 2));
      *(float4*)(b)     = *(const float4*)(bk2 + (tx << 2));
      *(float4*)(b + 4) = *(const float4*)(bk2 + 64 + (tx << 2));
#pragma unroll
      for (int i = 0; i < 8; ++i)
#pragma unroll
        for (int j = 0; j < 8; ++j)
          acc[i][j] = fmaf(a[i], b[j], acc[i][j]);
    }
    __syncthreads();
  }
#pragma unroll
  for (int i = 0; i < 8; ++i) {
    const int rr = row0 + ((i < 4) ? ((ty << 2) + i) : (64 + (ty << 2) + i - 4));
    size_t orow;
    if (mode == 0) orow = (size_t)(rr & 7) * NQ + (rr >> 3);
    else           orow = (size_t)rr;
#pragma unroll
    for (int jh = 0; jh < 2; ++jh) {
      const int cc = col0 + (jh << 6) + (tx << 2);
      const float4 bv4 = *(const float4*)(bias + cc);
      float4 o;
      o.x = acc[i][jh * 4 + 0] + bv4.x;
      o.y = acc[i][jh * 4 + 1] + bv4.y;
      o.z = acc[i][jh * 4 + 2] + bv4.z;
      o.w = acc[i][jh * 4 + 3] + bv4.w;
      *(float4*)(out + orow * CD + cc) = o;
    }
  }
}

// ---------------------------------------------------------------------------
// l2norm over rows of 640 (one wave per row)
// ---------------------------------------------------------------------------
__global__ __launch_bounds__(256)
void k_l2norm(float* __restrict__ X)
{
  const int row = (blockIdx.x << 2) + (threadIdx.x >> 6);
  const int lane = threadIdx.x & 63;
  float2* p2 = (float2*)(X + (size_t)row * CD);
  float ss = 0.f;
#pragma unroll
  for (int i = 0; i < 5; ++i) {
    float2 v = p2[lane + (i << 6)];
    ss = fmaf(v.x, v.x, fmaf(v.y, v.y, ss));
  }
  ss = wave_reduce_sum(ss);
  const float inv = 1.0f / fmaxf(sqrtf(ss), 1e-12f);
#pragma unroll
  for (int i = 0; i < 5; ++i) {
    float2 v = p2[lane + (i << 6)];
    v.x *= inv; v.y *= inv;
    p2[lane + (i << 6)] = v;
  }
}

// ---------------------------------------------------------------------------
// sim GEMM (NT, batched): E[b][m][n] = exp((k[b][m]·q[b][n] - 1) * 20)
// ---------------------------------------------------------------------------
__global__ __launch_bounds__(256)
void gemm_sim(const float* __restrict__ kb, const float* __restrict__ qb,
              float* __restrict__ E)
{
  __shared__ float As[32 * 132];
  __shared__ float Bs[32 * 132];
  const int tid = threadIdx.x;
  const int b = blockIdx.z;
  const int row0 = blockIdx.x << 7;
  const int col0 = blockIdx.y << 7;
  const int ty = tid >> 4, tx = tid & 15;
  const float* A = kb + (size_t)b * MK * CD;
  const float* Bq = qb + (size_t)b * NQ * CD;
  float acc[8][8];
#pragma unroll
  for (int i = 0; i < 8; ++i)
#pragma unroll
    for (int j = 0; j < 8; ++j) acc[i][j] = 0.f;

  for (int k0 = 0; k0 < CD; k0 += 32) {
    const float* Ap = A + (size_t)row0 * CD + k0;
    const float* Bp = Bq + (size_t)col0 * CD + k0;
#pragma unroll
    for (int t = 0; t < 4; ++t) {
      const int e = tid + (t << 8);
      const int r = e >> 3;
      const int kq = (e & 7) << 2;
      const float4 ga = *(const float4*)(Ap + (size_t)r * CD + kq);
      As[(kq + 0) * 132 + r] = ga.x;
      As[(kq + 1) * 132 + r] = ga.y;
      As[(kq + 2) * 132 + r] = ga.z;
      As[(kq + 3) * 132 + r] = ga.w;
      const float4 gb = *(const float4*)(Bp + (size_t)r * CD + kq);
      Bs[(kq + 0) * 132 + r] = gb.x;
      Bs[(kq + 1) * 132 + r] = gb.y;
      Bs[(kq + 2) * 132 + r] = gb.z;
      Bs[(kq + 3) * 132 + r] = gb.w;
    }
    __syncthreads();
#pragma unroll
    for (int k = 0; k < 32; ++k) {
      const float* ak = As + k * 132;
      const float* bk2 = Bs + k * 132;
      float a[8], bb[8];
      *(float4*)(a)      = *(const float4*)(ak + (ty << 2));
      *(float4*)(a + 4)  = *(const float4*)(ak + 64 + (ty << 2));
      *(float4*)(bb)     = *(const float4*)(bk2 + (tx << 2));
      *(float4*)(bb + 4) = *(const float4*)(bk2 + 64 + (tx << 2));
#pragma unroll
      for (int i = 0; i < 8; ++i)
#pragma unroll
        for (int j = 0; j < 8; ++j)
          acc[i][j] = fmaf(a[i], bb[j], acc[i][j]);
    }
    __syncthreads();
  }
#pragma unroll
  for (int i = 0; i < 8; ++i) {
    const int rr = row0 + ((i < 4) ? ((ty << 2) + i) : (64 + (ty << 2) + i - 4));
    const size_t ebase = ((size_t)b * MK + rr) * NQ;
#pragma unroll
    for (int jh = 0; jh < 2; ++jh) {
      const int cc = col0 + (jh << 6) + (tx << 2);
      float4 o;
      o.x = __expf((acc[i][jh * 4 + 0] - 1.f) * INV_EPS);
      o.y = __expf((acc[i][jh * 4 + 1] - 1.f) * INV_EPS);
      o.z = __expf((acc[i][jh * 4 + 2] - 1.f) * INV_EPS);
      o.w = __expf((acc[i][jh * 4 + 3] - 1.f) * INV_EPS);
      *(float4*)(E + ebase + cc) = o;
    }
  }
}

// ---------------------------------------------------------------------------
// Per-batch spin barrier: release-RMW arrival (agent scope), RELAXED polling,
// workgroup-acquire fence on exit. Payload moves via sc1 relaxed atomics.
// ---------------------------------------------------------------------------
__device__ __forceinline__ void wg_barrier(unsigned* ctr, unsigned target) {
  __syncthreads();   // drains each wave's vmcnt -> payload stores complete
  if (threadIdx.x == 0) {
    __hip_atomic_fetch_add(ctr, 1u, __ATOMIC_RELEASE, __HIP_MEMORY_SCOPE_AGENT);
    while (__hip_atomic_load(ctr, __ATOMIC_RELAXED, __HIP_MEMORY_SCOPE_AGENT) < target)
      __builtin_amdgcn_s_sleep(2);
    __builtin_amdgcn_fence(__ATOMIC_ACQUIRE, "workgroup");
  }
  __syncthreads();
}

// ---------------------------------------------------------------------------
// Fused persistent Sinkhorn, ONE barrier per iteration:
//  - 128 WGs x 512 threads; batch b = blockIdx&7, group g = blockIdx>>3 (16/batch)
//  - WG holds 64 E-rows in registers: e[8][16]/lane (8 waves x 8 rows)
//  - per iter: local u-phase -> LDS col-partial reduce -> publish 1024-float
//    slice (parity double-buffered) -> barrier(16 arrivals) -> EVERY WG reads
//    all 16 partials and computes the FULL w vector locally into LDS.
// ---------------------------------------------------------------------------
__global__ __launch_bounds__(512, 2)
void k_sinkhorn(const float* __restrict__ E, const int* __restrict__ maskI,
                const float* __restrict__ muVal, float* __restrict__ w,
                float* __restrict__ z, float* __restrict__ attn,
                float* __restrict__ part, unsigned* __restrict__ barCtr)
{
  const int b = blockIdx.x & 7;        // XCD-affinity: 16 WGs of batch b co-locate
  const int g = blockIdx.x >> 3;       // 0..15
  const int tid = threadIdx.x;
  const int wave = tid >> 6, lane = tid & 63;
  const int m0 = (g << 6) + (wave << 3);      // first of this wave's 8 rows
  const float* Eb = E + ((size_t)b << 20);
  float* wb = w + (b << 10);
  unsigned* ctr = barCtr + b * 32;

  __shared__ float wS[1024];
  __shared__ float colRed[8][1024];

  // load 8 rows x 16 col-chunks into registers
  float e[8][16];
#pragma unroll
  for (int r = 0; r < 8; ++r) {
    const float* row = Eb + ((size_t)(m0 + r) << 10) + lane;
#pragma unroll
    for (int j = 0; j < 16; ++j) e[r][j] = row[j << 6];
  }
  float rmask[8];
#pragma unroll
  for (int r = 0; r < 8; ++r)
    rmask[r] = maskI[(b << 10) + m0 + r] ? 1.f : 0.f;
  const float muT = muVal[b];
  const float nuT = 1.0f / (float)NQ + 1e-8f;
  float zr[8];
#pragma unroll
  for (int r = 0; r < 8; ++r) zr[r] = 0.f;

  // w starts at 1.0
  wS[tid] = 1.0f; wS[tid + 512] = 1.0f;
  __syncthreads();

  unsigned gen = 0;
  for (int it = 0; it < 100; ++it) {
    const int p = it & 1;
    float* partP = part + (size_t)(((p << 3) + b) << 14);   // [16][1024] slice base
    // hoist w into regs
    float wv[16];
#pragma unroll
    for (int j = 0; j < 16; ++j) wv[j] = wS[lane + (j << 6)];
    // u-phase: z for own rows
#pragma unroll
    for (int r = 0; r < 8; ++r) {
      float s = 0.f;
#pragma unroll
      for (int j = 0; j < 16; ++j) s = fmaf(e[r][j], wv[j], s);
      s = wave_reduce_sum(s);
      zr[r] = rmask[r] * (muT / fmaxf(s, 1e-35f));
    }
    // column partials across own 8 rows -> per-wave vector in LDS
#pragma unroll
    for (int j = 0; j < 16; ++j) {
      float pj = 0.f;
#pragma unroll
      for (int r = 0; r < 8; ++r) pj = fmaf(e[r][j], zr[r], pj);
      colRed[wave][lane + (j << 6)] = pj;
    }
    __syncthreads();
    // reduce 8 waves, publish WG's 1024-float partial slice
    for (int n = tid; n < 1024; n += 512) {
      float s = 0.f;
#pragma unroll
      for (int ww = 0; ww < 8; ++ww) s += colRed[ww][n];
      g_store(partP + (g << 10) + n, s);
    }
    ++gen; wg_barrier(ctr, gen << 4);   // 16 arrivals per batch
    // every WG: reduce all 16 partials -> full w vector into LDS
    for (int n = tid; n < 1024; n += 512) {
      float s = 0.f;
#pragma unroll
      for (int gg = 0; gg < 16; ++gg) s += g_load(partP + (gg << 10) + n);
      wS[n] = nuT / fmaxf(s, 1e-35f);
    }
    __syncthreads();
  }

  // epilogue: attn + z with final z (iter-100 u) and final w (iter-100 v, in wS)
  {
    float wv[16];
#pragma unroll
    for (int j = 0; j < 16; ++j) wv[j] = wS[lane + (j << 6)];
#pragma unroll
    for (int r = 0; r < 8; ++r) {
      float s = 0.f;
#pragma unroll
      for (int j = 0; j < 16; ++j) {
        const float ee = e[r][j];
        s += (1.f + EPS_OT * __logf(ee)) * ee * wv[j];
      }
      s = wave_reduce_sum(s);
      if (!lane) {
        const int m = (b << 10) + m0 + r;
        z[m] = zr[r];
        attn[m] = 1048576.0f * zr[r] * s;   // M*Nq
      }
    }
    // publish final w for gemm_x (all 16 WGs write identical values - benign)
    for (int n = tid; n < 1024; n += 512) wb[n] = wS[n];
  }
}

// ---------------------------------------------------------------------------
// Final: out[(n*8+b)][c] = w[b][n]*sum_m (z[b][m]*E[b][m][n])*vp[b][m][c] + bp[c]
// ---------------------------------------------------------------------------
__global__ __launch_bounds__(256)
void gemm_x(const float* __restrict__ E, const float* __restrict__ vp,
            const float* __restrict__ z, const float* __restrict__ w,
            const float* __restrict__ bp, float* __restrict__ out)
{
  __shared__ float Ts[32 * 132];
  __shared__ float Vs[32 * 132];
  const int tid = threadIdx.x;
  const int b = blockIdx.z;
  const int n0 = blockIdx.x << 7;
  const int c0 = blockIdx.y << 7;
  const int ty = tid >> 4, tx = tid & 15;
  const float* Eb = E + ((size_t)b << 20);
  const float* Vb = vp + (size_t)b * MK * CD;
  const float* zb = z + (b << 10);
  float acc[8][8];
#pragma unroll
  for (int i = 0; i < 8; ++i)
#pragma unroll
    for (int j = 0; j < 8; ++j) acc[i][j] = 0.f;

  for (int m0 = 0; m0 < MK; m0 += 32) {
#pragma unroll
    for (int t = 0; t < 4; ++t) {
      const int e = tid + (t << 8);
      const int c4 = (e & 31) << 2;
      const int k = e >> 5;
      const float zk = zb[m0 + k];
      const float4 g = *(const float4*)(Eb + ((size_t)(m0 + k) << 10) + n0 + c4);
      float4 tv;
      tv.x = g.x * zk; tv.y = g.y * zk; tv.z = g.z * zk; tv.w = g.w * zk;
      *(float4*)(Ts + k * 132 + c4) = tv;
      const float4 gv = *(const float4*)(Vb + (size_t)(m0 + k) * CD + c0 + c4);
      *(float4*)(Vs + k * 132 + c4) = gv;
    }
    __syncthreads();
#pragma unroll
    for (int k = 0; k < 32; ++k) {
      const float* ak = Ts + k * 132;
      const float* bk2 = Vs + k * 132;
      float a[8], bb[8];
      *(float4*)(a)      = *(const float4*)(ak + (ty << 2));
      *(float4*)(a + 4)  = *(const float4*)(ak + 64 + (ty << 2));
      *(float4*)(bb)     = *(const float4*)(bk2 + (tx << 2));
      *(float4*)(bb + 4) = *(const float4*)(bk2 + 64 + (tx << 2));
#pragma unroll
      for (int i = 0; i < 8; ++i)
#pragma unroll
        for (int j = 0; j < 8; ++j)
          acc[i][j] = fmaf(a[i], bb[j], acc[i][j]);
    }
    __syncthreads();
  }
#pragma unroll
  for (int i = 0; i < 8; ++i) {
    const int nrow = n0 + ((i < 4) ? ((ty << 2) + i) : (64 + (ty << 2) + i - 4));
    const float wn = w[(b << 10) + nrow];
    const size_t obase = (size_t)((nrow << 3) + b) * CD;
#pragma unroll
    for (int jh = 0; jh < 2; ++jh) {
      const int cc = c0 + (jh << 6) + (tx << 2);
      const float4 bp4 = *(const float4*)(bp + cc);
      float4 o;
      o.x = acc[i][jh * 4 + 0] * wn + bp4.x;
      o.y = acc[i][jh * 4 + 1] * wn + bp4.y;
      o.z = acc[i][jh * 4 + 2] * wn + bp4.z;
      o.w = acc[i][jh * 4 + 3] * wn + bp4.w;
      *(float4*)(out + obase + cc) = o;
    }
  }
}

// ---------------------------------------------------------------------------
extern "C" void kernel_launch(void* const* d_in, const int* in_sizes, int n_in,
                              void* d_out, int out_size, void* d_ws, size_t ws_size,
                              hipStream_t stream)
{
  const float* xq = (const float*)d_in[0];
  const float* xk = (const float*)d_in[1];
  const float* xv = (const float*)d_in[2];
  const void*  maskRaw = d_in[3];
  const float* Wq = (const float*)d_in[4];
  const float* bq = (const float*)d_in[5];
  const float* Wk = (const float*)d_in[6];
  const float* bk = (const float*)d_in[7];
  const float* Wv = (const float*)d_in[8];
  const float* bv = (const float*)d_in[9];
  const float* Wp = (const float*)d_in[10];
  const float* bp = (const float*)d_in[11];

  float* out  = (float*)d_out;
  float* attn = out + (size_t)NQ * B_DIM * CD;

  float* qb  = (float*)d_ws;                      // [B][Nq][C]
  float* kb  = qb + (size_t)B_DIM * NQ * CD;      // [B][M][C]
  float* vpb = kb + (size_t)B_DIM * MK * CD;      // [B][M][C]  (v @ Wp.T)
  float* E   = vpb + (size_t)B_DIM * MK * CD;     // [B][M][Nq]
  float* z   = E + (size_t)B_DIM * MK * NQ;       // [B][M]
  float* w   = z + B_DIM * MK;                    // [B][Nq]
  int*   maskI = (int*)(w + B_DIM * NQ);          // [B][M]
  float* muVal = (float*)(maskI + B_DIM * MK);    // [B]
  unsigned* barCtr = (unsigned*)(muVal + B_DIM);  // [8*32]
  // overlays (dead regions at time of use):
  float* A    = E;                                // 640*640, dead before sim
  float* bvp  = E + CD * CD;                      // 640
  float* part = qb;                               // [2][B][16][1024], qb dead after sim

  k_combineA<<<dim3(10, 10), 256, 0, stream>>>(Wp, Wv, A);
  k_bvp<<<160, 256, 0, stream>>>(Wp, bv, bvp);
  k_setup<<<1, 1024, 0, stream>>>(maskRaw, maskI, muVal, w, barCtr);

  gemm_proj3<<<dim3(64, 5, 3), 256, 0, stream>>>(xq, xk, xv, Wq, bq, Wk, bk,
                                                 A, bvp, qb, kb, vpb);
  k_l2norm<<<4096, 256, 0, stream>>>(qb);   // qb,kb contiguous: 16384 rows

  gemm_sim<<<dim3(8, 8, 8), 256, 0, stream>>>(kb, qb, E);

  {
    void* args[] = {(void*)&E, (void*)&maskI, (void*)&muVal, (void*)&w,
                    (void*)&z, (void*)&attn, (void*)&part, (void*)&barCtr};
    hipLaunchCooperativeKernel((void*)k_sinkhorn, dim3(128), dim3(512),
                               args, 0, stream);
  }

  gemm_x<<<dim3(8, 5, 8), 256, 0, stream>>>(E, vpb, z, w, bp, out);
}

// Round 5
// 815.141 us; speedup vs baseline: 7.2440x; 1.5785x over previous
//
#include <hip/hip_runtime.h>
#include <cstdint>
#include <cstddef>

#define B_DIM 8
#define NQ    1024
#define MK    1024
#define CD    640
#define INV_EPS 20.0f
#define EPS_OT  0.05f

typedef unsigned short u16;
typedef __attribute__((ext_vector_type(8))) short bf16x8;
typedef __attribute__((ext_vector_type(4))) float f32x4;

#define GLDS(gp, lp) __builtin_amdgcn_global_load_lds( \
    (const __attribute__((address_space(1))) void*)(gp), \
    (__attribute__((address_space(3))) void*)(lp), 16, 0, 0)

static __device__ __forceinline__ float wave_reduce_sum(float s) {
#pragma unroll
  for (int off = 32; off; off >>= 1) s += __shfl_xor(s, off, 64);
  return s;
}

static __device__ __forceinline__ u16 f2bf(float f) {
  uint32_t u = __float_as_uint(f);
  u += 0x7fff + ((u >> 16) & 1);     // RNE
  return (u16)(u >> 16);
}

// Device-scope relaxed accesses (per-access sc1, no L2 flush storms)
static __device__ __forceinline__ void g_store(float* p, float v) {
  __hip_atomic_store(p, v, __ATOMIC_RELAXED, __HIP_MEMORY_SCOPE_AGENT);
}
static __device__ __forceinline__ float g_load(const float* p) {
  return __hip_atomic_load((float*)p, __ATOMIC_RELAXED, __HIP_MEMORY_SCOPE_AGENT);
}

// ---------------------------------------------------------------------------
// Setup: detect mask dtype, build maskI, per-batch mu, w=1, zero barrier ctrs
// ---------------------------------------------------------------------------
__global__ void k_setup(const void* __restrict__ maskRaw, int* __restrict__ maskI,
                        float* __restrict__ muVal, float* __restrict__ w,
                        unsigned* __restrict__ barCtr)
{
  __shared__ int s_flag;
  __shared__ int s_cnt[B_DIM];
  const int tid = threadIdx.x;
  if (tid == 0) s_flag = 0;
  if (tid < B_DIM) s_cnt[tid] = 0;
  if (tid < 256) barCtr[tid] = 0u;
  __syncthreads();

  const unsigned char* mb = (const unsigned char*)maskRaw;
  int local = 0;
  for (int i = tid; i < B_DIM * MK; i += 1024)
    if ((i & 3) && mb[i]) local = 1;
  if (local) atomicOr(&s_flag, 1);
  __syncthreads();

  const int isByte = s_flag;
  const int* mi32 = (const int*)maskRaw;
  for (int i = tid; i < B_DIM * MK; i += 1024) {
    int v = isByte ? (int)mb[i] : mi32[i];
    v = v ? 1 : 0;
    maskI[i] = v;
    if (v) atomicAdd(&s_cnt[i >> 10], 1);
  }
  for (int i = tid; i < B_DIM * NQ; i += 1024) w[i] = 1.0f;
  __syncthreads();
  if (tid < B_DIM) {
    float c = (float)s_cnt[tid];
    muVal[tid] = (c > 0.f ? 1.0f / c : 1.0f / (float)MK) + 1e-8f;
  }
}

// ---------------------------------------------------------------------------
// fp32 -> bf16 conversion for xq, xk, xv, Wq, Wk (fused, grid.y selects)
// ---------------------------------------------------------------------------
__global__ __launch_bounds__(256)
void k_cvt5(const float* __restrict__ x0, u16* __restrict__ d0,
            const float* __restrict__ x1, u16* __restrict__ d1,
            const float* __restrict__ x2, u16* __restrict__ d2,
            const float* __restrict__ x3, u16* __restrict__ d3,
            const float* __restrict__ x4, u16* __restrict__ d4)
{
  const int a = blockIdx.y;
  const float* s; u16* d; int n;
  if      (a == 0) { s = x0; d = d0; n = 8192 * CD; }
  else if (a == 1) { s = x1; d = d1; n = 8192 * CD; }
  else if (a == 2) { s = x2; d = d2; n = 8192 * CD; }
  else if (a == 3) { s = x3; d = d3; n = CD * CD; }
  else             { s = x4; d = d4; n = CD * CD; }
  const int i = (blockIdx.x * 256 + threadIdx.x) * 4;
  if (i >= n) return;
  const float4 v = *(const float4*)(s + i);
  *(ushort4*)(d + i) = make_ushort4(f2bf(v.x), f2bf(v.y), f2bf(v.z), f2bf(v.w));
}

// ---------------------------------------------------------------------------
// Ah = bf16(Wp @ Wv)  (A[c][k] = sum_j Wp[c][j]*Wv[j][k]) fp32 compute
// ---------------------------------------------------------------------------
__global__ __launch_bounds__(256)
void k_combineA(const float* __restrict__ Wp, const float* __restrict__ Wv,
                u16* __restrict__ Ah)
{
  __shared__ float Ps[32][68];
  __shared__ float Vs[32][68];
  const int tid = threadIdx.x;
  const int c0 = blockIdx.x << 6, k0 = blockIdx.y << 6;
  const int ty = tid >> 4, tx = tid & 15;
  float acc[4][4];
#pragma unroll
  for (int i = 0; i < 4; ++i)
#pragma unroll
    for (int j = 0; j < 4; ++j) acc[i][j] = 0.f;

  for (int j0 = 0; j0 < CD; j0 += 32) {
    {
      const int c = tid >> 2, j4 = (tid & 3) << 3;
      const float* p = Wp + (size_t)(c0 + c) * CD + j0 + j4;
      float4 u0 = *(const float4*)p, u1 = *(const float4*)(p + 4);
      Ps[j4 + 0][c] = u0.x; Ps[j4 + 1][c] = u0.y; Ps[j4 + 2][c] = u0.z; Ps[j4 + 3][c] = u0.w;
      Ps[j4 + 4][c] = u1.x; Ps[j4 + 5][c] = u1.y; Ps[j4 + 6][c] = u1.z; Ps[j4 + 7][c] = u1.w;
    }
    {
      const int j = tid >> 3, k4 = (tid & 7) << 3;
      const float* p = Wv + (size_t)(j0 + j) * CD + k0 + k4;
      float4 u0 = *(const float4*)p, u1 = *(const float4*)(p + 4);
      *(float4*)&Vs[j][k4] = u0; *(float4*)&Vs[j][k4 + 4] = u1;
    }
    __syncthreads();
#pragma unroll
    for (int j = 0; j < 32; ++j) {
      float a[4], b[4];
      *(float4*)a = *(const float4*)&Ps[j][ty << 2];
      *(float4*)b = *(const float4*)&Vs[j][tx << 2];
#pragma unroll
      for (int i = 0; i < 4; ++i)
#pragma unroll
        for (int jj = 0; jj < 4; ++jj)
          acc[i][jj] = fmaf(a[i], b[jj], acc[i][jj]);
    }
    __syncthreads();
  }
#pragma unroll
  for (int i = 0; i < 4; ++i) {
    *(ushort4*)(Ah + (size_t)(c0 + (ty << 2) + i) * CD + k0 + (tx << 2)) =
      make_ushort4(f2bf(acc[i][0]), f2bf(acc[i][1]), f2bf(acc[i][2]), f2bf(acc[i][3]));
  }
}

// bvp[c] = sum_j Wp[c][j]*bv[j]
__global__ __launch_bounds__(256)
void k_bvp(const float* __restrict__ Wp, const float* __restrict__ bv,
           float* __restrict__ bvp)
{
  const int c = (blockIdx.x << 2) + (threadIdx.x >> 6);
  const int lane = threadIdx.x & 63;
  float s = 0.f;
  for (int j = lane; j < CD; j += 64) s = fmaf(Wp[(size_t)c * CD + j], bv[j], s);
  s = wave_reduce_sum(s);
  if (!lane) bvp[c] = s;
}

// ---------------------------------------------------------------------------
// MFMA NT GEMM core (shared pattern): 128x128 tile, BK=32, 256 thr / 4 waves.
// LDS tiles [128 rows][32 k] bf16 with XOR chunk-swizzle (glds-compatible).
// ---------------------------------------------------------------------------
// Projections: mode 0: qb = perm(xq@Wq^T)+bq ; 1: kb = xk@Wk^T+bk ; 2: vp = xv@Ah^T+bvp
__global__ __launch_bounds__(256)
void mfma_proj(const u16* __restrict__ xqh, const u16* __restrict__ xkh,
               const u16* __restrict__ xvh,
               const u16* __restrict__ Wqh, const u16* __restrict__ Wkh,
               const u16* __restrict__ Ah,
               const float* __restrict__ bq, const float* __restrict__ bk,
               const float* __restrict__ bvp,
               float* __restrict__ qb, float* __restrict__ kb,
               float* __restrict__ vp)
{
  __shared__ u16 As[128 * 32];
  __shared__ u16 Bs[128 * 32];
  const int mode = blockIdx.z;
  const u16* X     = (mode == 0) ? xqh : ((mode == 1) ? xkh : xvh);
  const u16* W     = (mode == 0) ? Wqh : ((mode == 1) ? Wkh : Ah);
  const float* bias= (mode == 0) ? bq  : ((mode == 1) ? bk  : bvp);
  float* outp      = (mode == 0) ? qb  : ((mode == 1) ? kb  : vp);

  const int tid = threadIdx.x, wave = tid >> 6, lane = tid & 63;
  const int row0 = blockIdx.x << 7, col0 = blockIdx.y << 7;

  // staging addresses
  const int rS = (wave << 5) + (lane >> 2);        // local row, instr 0
  const int pc = lane & 3;
  const int kc0 = pc ^ ((rS >> 1) & 3);
  const int kc1 = pc ^ (((rS + 16) >> 1) & 3);
  const u16* gA0 = X + (size_t)(row0 + rS) * CD + (kc0 << 3);
  const u16* gA1 = X + (size_t)(row0 + rS + 16) * CD + (kc1 << 3);
  const u16* gB0 = W + (size_t)(col0 + rS) * CD + (kc0 << 3);
  const u16* gB1 = W + (size_t)(col0 + rS + 16) * CD + (kc1 << 3);
  u16* lA = As + (wave << 10);
  u16* lB = Bs + (wave << 10);

  // fragment read offsets (u16 units), fixed per lane
  const int wm0 = (wave & 1) << 6, wn0 = (wave >> 1) << 6;
  int aOff[4], bOff[4];
#pragma unroll
  for (int t = 0; t < 4; ++t) {
    const int ra = wm0 + (t << 4) + (lane & 15);
    aOff[t] = ra * 32 + (((lane >> 4) ^ ((ra >> 1) & 3)) << 3);
    const int rb = wn0 + (t << 4) + (lane & 15);
    bOff[t] = rb * 32 + (((lane >> 4) ^ ((rb >> 1) & 3)) << 3);
  }
  f32x4 acc[4][4];
#pragma unroll
  for (int i = 0; i < 4; ++i)
#pragma unroll
    for (int j = 0; j < 4; ++j) acc[i][j] = {0.f, 0.f, 0.f, 0.f};

  for (int k0 = 0; k0 < CD; k0 += 32) {
    __syncthreads();
    GLDS(gA0, lA); GLDS(gA1, lA + 512);
    GLDS(gB0, lB); GLDS(gB1, lB + 512);
    gA0 += 32; gA1 += 32; gB0 += 32; gB1 += 32;
    __syncthreads();
    bf16x8 a[4], b[4];
#pragma unroll
    for (int t = 0; t < 4; ++t) {
      a[t] = *(const bf16x8*)(As + aOff[t]);
      b[t] = *(const bf16x8*)(Bs + bOff[t]);
    }
#pragma unroll
    for (int i = 0; i < 4; ++i)
#pragma unroll
      for (int j = 0; j < 4; ++j)
        acc[i][j] = __builtin_amdgcn_mfma_f32_16x16x32_bf16(a[i], b[j], acc[i][j], 0, 0, 0);
  }

  // epilogue: bias + store (D: row = quad*4+reg, col = lane&15)
  float bv4[4];
  int ccs[4];
#pragma unroll
  for (int j = 0; j < 4; ++j) {
    ccs[j] = col0 + wn0 + (j << 4) + (lane & 15);
    bv4[j] = bias[ccs[j]];
  }
#pragma unroll
  for (int i = 0; i < 4; ++i) {
    const int rbase = row0 + wm0 + (i << 4) + ((lane >> 4) << 2);
#pragma unroll
    for (int r = 0; r < 4; ++r) {
      const int rr = rbase + r;
      const size_t orow = (mode == 0) ? ((size_t)(rr & 7) * NQ + (rr >> 3)) : (size_t)rr;
      float* op = outp + orow * CD;
#pragma unroll
      for (int j = 0; j < 4; ++j)
        op[ccs[j]] = acc[i][j][r] + bv4[j];
    }
  }
}

// sim: E[b][m][n] = exp((k̂[m]·q̂[n] - 1)*20), A=kbh, B=qbh, K=640
__global__ __launch_bounds__(256)
void mfma_sim(const u16* __restrict__ kbh, const u16* __restrict__ qbh,
              float* __restrict__ E)
{
  __shared__ u16 As[128 * 32];
  __shared__ u16 Bs[128 * 32];
  const int tid = threadIdx.x, wave = tid >> 6, lane = tid & 63;
  const int b = blockIdx.z;
  const int row0 = blockIdx.x << 7, col0 = blockIdx.y << 7;
  const u16* A = kbh + (size_t)b * MK * CD;
  const u16* B = qbh + (size_t)b * NQ * CD;

  const int rS = (wave << 5) + (lane >> 2);
  const int pc = lane & 3;
  const int kc0 = pc ^ ((rS >> 1) & 3);
  const int kc1 = pc ^ (((rS + 16) >> 1) & 3);
  const u16* gA0 = A + (size_t)(row0 + rS) * CD + (kc0 << 3);
  const u16* gA1 = A + (size_t)(row0 + rS + 16) * CD + (kc1 << 3);
  const u16* gB0 = B + (size_t)(col0 + rS) * CD + (kc0 << 3);
  const u16* gB1 = B + (size_t)(col0 + rS + 16) * CD + (kc1 << 3);
  u16* lA = As + (wave << 10);
  u16* lB = Bs + (wave << 10);

  const int wm0 = (wave & 1) << 6, wn0 = (wave >> 1) << 6;
  int aOff[4], bOff[4];
#pragma unroll
  for (int t = 0; t < 4; ++t) {
    const int ra = wm0 + (t << 4) + (lane & 15);
    aOff[t] = ra * 32 + (((lane >> 4) ^ ((ra >> 1) & 3)) << 3);
    const int rb = wn0 + (t << 4) + (lane & 15);
    bOff[t] = rb * 32 + (((lane >> 4) ^ ((rb >> 1) & 3)) << 3);
  }
  f32x4 acc[4][4];
#pragma unroll
  for (int i = 0; i < 4; ++i)
#pragma unroll
    for (int j = 0; j < 4; ++j) acc[i][j] = {0.f, 0.f, 0.f, 0.f};

  for (int k0 = 0; k0 < CD; k0 += 32) {
    __syncthreads();
    GLDS(gA0, lA); GLDS(gA1, lA + 512);
    GLDS(gB0, lB); GLDS(gB1, lB + 512);
    gA0 += 32; gA1 += 32; gB0 += 32; gB1 += 32;
    __syncthreads();
    bf16x8 a[4], b[4];
#pragma unroll
    for (int t = 0; t < 4; ++t) {
      a[t] = *(const bf16x8*)(As + aOff[t]);
      b[t] = *(const bf16x8*)(Bs + bOff[t]);
    }
#pragma unroll
    for (int i = 0; i < 4; ++i)
#pragma unroll
      for (int j = 0; j < 4; ++j)
        acc[i][j] = __builtin_amdgcn_mfma_f32_16x16x32_bf16(a[i], b[j], acc[i][j], 0, 0, 0);
  }

#pragma unroll
  for (int i = 0; i < 4; ++i) {
    const int rbase = row0 + wm0 + (i << 4) + ((lane >> 4) << 2);
#pragma unroll
    for (int r = 0; r < 4; ++r) {
      const int rr = rbase + r;
      float* erow = E + (((size_t)(b << 10) + rr) << 10);
#pragma unroll
      for (int j = 0; j < 4; ++j) {
        const int cc = col0 + wn0 + (j << 4) + (lane & 15);
        erow[cc] = __expf((acc[i][j][r] - 1.f) * INV_EPS);
      }
    }
  }
}

// gemm_x: out[(n*8+b)][c] = w[n]*sum_m Et[n][m]*Vpt[c][m] + bp[c], K=1024
__global__ __launch_bounds__(256)
void mfma_x(const u16* __restrict__ Et, const u16* __restrict__ Vpt,
            const float* __restrict__ w, const float* __restrict__ bp,
            float* __restrict__ out)
{
  __shared__ u16 As[128 * 32];
  __shared__ u16 Bs[128 * 32];
  const int tid = threadIdx.x, wave = tid >> 6, lane = tid & 63;
  const int b = blockIdx.z;
  const int row0 = blockIdx.x << 7;   // n
  const int col0 = blockIdx.y << 7;   // c
  const u16* A = Et + ((size_t)b << 20);
  const u16* B = Vpt + (size_t)b * CD * MK;

  const int rS = (wave << 5) + (lane >> 2);
  const int pc = lane & 3;
  const int kc0 = pc ^ ((rS >> 1) & 3);
  const int kc1 = pc ^ (((rS + 16) >> 1) & 3);
  const u16* gA0 = A + ((size_t)(row0 + rS) << 10) + (kc0 << 3);
  const u16* gA1 = A + ((size_t)(row0 + rS + 16) << 10) + (kc1 << 3);
  const u16* gB0 = B + ((size_t)(col0 + rS) << 10) + (kc0 << 3);
  const u16* gB1 = B + ((size_t)(col0 + rS + 16) << 10) + (kc1 << 3);
  u16* lA = As + (wave << 10);
  u16* lB = Bs + (wave << 10);

  const int wm0 = (wave & 1) << 6, wn0 = (wave >> 1) << 6;
  int aOff[4], bOff[4];
#pragma unroll
  for (int t = 0; t < 4; ++t) {
    const int ra = wm0 + (t << 4) + (lane & 15);
    aOff[t] = ra * 32 + (((lane >> 4) ^ ((ra >> 1) & 3)) << 3);
    const int rb = wn0 + (t << 4) + (lane & 15);
    bOff[t] = rb * 32 + (((lane >> 4) ^ ((rb >> 1) & 3)) << 3);
  }
  f32x4 acc[4][4];
#pragma unroll
  for (int i = 0; i < 4; ++i)
#pragma unroll
    for (int j = 0; j < 4; ++j) acc[i][j] = {0.f, 0.f, 0.f, 0.f};

  for (int k0 = 0; k0 < MK; k0 += 32) {
    __syncthreads();
    GLDS(gA0, lA); GLDS(gA1, lA + 512);
    GLDS(gB0, lB); GLDS(gB1, lB + 512);
    gA0 += 32; gA1 += 32; gB0 += 32; gB1 += 32;
    __syncthreads();
    bf16x8 a[4], b[4];
#pragma unroll
    for (int t = 0; t < 4; ++t) {
      a[t] = *(const bf16x8*)(As + aOff[t]);
      b[t] = *(const bf16x8*)(Bs + bOff[t]);
    }
#pragma unroll
    for (int i = 0; i < 4; ++i)
#pragma unroll
      for (int j = 0; j < 4; ++j)
        acc[i][j] = __builtin_amdgcn_mfma_f32_16x16x32_bf16(a[i], b[j], acc[i][j], 0, 0, 0);
  }

  float bv4[4];
  int ccs[4];
#pragma unroll
  for (int j = 0; j < 4; ++j) {
    ccs[j] = col0 + wn0 + (j << 4) + (lane & 15);
    bv4[j] = bp[ccs[j]];
  }
#pragma unroll
  for (int i = 0; i < 4; ++i) {
    const int rbase = row0 + wm0 + (i << 4) + ((lane >> 4) << 2);
#pragma unroll
    for (int r = 0; r < 4; ++r) {
      const int rr = rbase + r;           // n index
      const float wn = w[(b << 10) + rr];
      float* op = out + ((size_t)rr * 8 + b) * CD;
#pragma unroll
      for (int j = 0; j < 4; ++j)
        op[ccs[j]] = acc[i][j][r] * wn + bv4[j];
    }
  }
}

// ---------------------------------------------------------------------------
// l2norm rows of 640 fp32 -> bf16 output
// ---------------------------------------------------------------------------
__global__ __launch_bounds__(256)
void k_l2bf(const float* __restrict__ X, u16* __restrict__ O)
{
  const int row = (blockIdx.x << 2) + (threadIdx.x >> 6);
  const int lane = threadIdx.x & 63;
  const float2* p2 = (const float2*)(X + (size_t)row * CD);
  float2 v[5];
  float ss = 0.f;
#pragma unroll
  for (int i = 0; i < 5; ++i) {
    v[i] = p2[lane + (i << 6)];
    ss = fmaf(v[i].x, v[i].x, fmaf(v[i].y, v[i].y, ss));
  }
  ss = wave_reduce_sum(ss);
  const float inv = 1.0f / fmaxf(sqrtf(ss), 1e-12f);
  ushort2* o2 = (ushort2*)(O + (size_t)row * CD);
#pragma unroll
  for (int i = 0; i < 5; ++i)
    o2[lane + (i << 6)] = make_ushort2(f2bf(v[i].x * inv), f2bf(v[i].y * inv));
}

// ---------------------------------------------------------------------------
// Transposes: vp[b][m][c] -> Vpt[b][c][m] bf16 ; E[b][m][n]*z[m] -> Et[b][n][m]
// ---------------------------------------------------------------------------
__global__ __launch_bounds__(256)
void k_vpt(const float* __restrict__ vp, u16* __restrict__ Vpt)
{
  __shared__ float t[64][65];
  const int b = blockIdx.z, m0 = blockIdx.y << 6, c0 = blockIdx.x << 6;
  const int tid = threadIdx.x;
  const int cc = tid & 63, r4 = tid >> 6;
#pragma unroll
  for (int i = 0; i < 16; ++i) {
    const int m = (i << 2) + r4;
    t[m][cc] = vp[((size_t)((b << 10) + m0 + m)) * CD + c0 + cc];
  }
  __syncthreads();
  const int mm = tid & 63;
#pragma unroll
  for (int i = 0; i < 16; ++i) {
    const int c = (i << 2) + r4;
    Vpt[((size_t)(b * CD + c0 + c) << 10) + m0 + mm] = f2bf(t[mm][c]);
  }
}

__global__ __launch_bounds__(256)
void k_et(const float* __restrict__ E, const float* __restrict__ z,
          u16* __restrict__ Et)
{
  __shared__ float t[64][65];
  const int b = blockIdx.z, m0 = blockIdx.y << 6, n0 = blockIdx.x << 6;
  const int tid = threadIdx.x;
  const int nn = tid & 63, r4 = tid >> 6;
#pragma unroll
  for (int i = 0; i < 16; ++i) {
    const int m = (i << 2) + r4;
    const float zm = z[(b << 10) + m0 + m];
    t[m][nn] = E[(((size_t)((b << 10) + m0 + m)) << 10) + n0 + nn] * zm;
  }
  __syncthreads();
  const int mm = tid & 63;
#pragma unroll
  for (int i = 0; i < 16; ++i) {
    const int n = (i << 2) + r4;
    Et[(((size_t)((b << 10) + n0 + n)) << 10) + m0 + mm] = f2bf(t[mm][n]);
  }
}

// ---------------------------------------------------------------------------
// Per-batch spin barrier (unchanged from round 4)
// ---------------------------------------------------------------------------
__device__ __forceinline__ void wg_barrier(unsigned* ctr, unsigned target) {
  __syncthreads();
  if (threadIdx.x == 0) {
    __hip_atomic_fetch_add(ctr, 1u, __ATOMIC_RELEASE, __HIP_MEMORY_SCOPE_AGENT);
    while (__hip_atomic_load(ctr, __ATOMIC_RELAXED, __HIP_MEMORY_SCOPE_AGENT) < target)
      __builtin_amdgcn_s_sleep(2);
    __builtin_amdgcn_fence(__ATOMIC_ACQUIRE, "workgroup");
  }
  __syncthreads();
}

// ---------------------------------------------------------------------------
// Fused persistent Sinkhorn (unchanged from round 4): 128 WGs x 512 thr,
// 64 E-rows/WG in registers, one barrier/iter.
// ---------------------------------------------------------------------------
__global__ __launch_bounds__(512, 2)
void k_sinkhorn(const float* __restrict__ E, const int* __restrict__ maskI,
                const float* __restrict__ muVal, float* __restrict__ w,
                float* __restrict__ z, float* __restrict__ attn,
                float* __restrict__ part, unsigned* __restrict__ barCtr)
{
  const int b = blockIdx.x & 7;
  const int g = blockIdx.x >> 3;
  const int tid = threadIdx.x;
  const int wave = tid >> 6, lane = tid & 63;
  const int m0 = (g << 6) + (wave << 3);
  const float* Eb = E + ((size_t)b << 20);
  float* wb = w + (b << 10);
  unsigned* ctr = barCtr + b * 32;

  __shared__ float wS[1024];
  __shared__ float colRed[8][1024];

  float e[8][16];
#pragma unroll
  for (int r = 0; r < 8; ++r) {
    const float* row = Eb + ((size_t)(m0 + r) << 10) + lane;
#pragma unroll
    for (int j = 0; j < 16; ++j) e[r][j] = row[j << 6];
  }
  float rmask[8];
#pragma unroll
  for (int r = 0; r < 8; ++r)
    rmask[r] = maskI[(b << 10) + m0 + r] ? 1.f : 0.f;
  const float muT = muVal[b];
  const float nuT = 1.0f / (float)NQ + 1e-8f;
  float zr[8];
#pragma unroll
  for (int r = 0; r < 8; ++r) zr[r] = 0.f;

  wS[tid] = 1.0f; wS[tid + 512] = 1.0f;
  __syncthreads();

  unsigned gen = 0;
  for (int it = 0; it < 100; ++it) {
    const int p = it & 1;
    float* partP = part + (size_t)(((p << 3) + b) << 14);
    float wv[16];
#pragma unroll
    for (int j = 0; j < 16; ++j) wv[j] = wS[lane + (j << 6)];
#pragma unroll
    for (int r = 0; r < 8; ++r) {
      float s = 0.f;
#pragma unroll
      for (int j = 0; j < 16; ++j) s = fmaf(e[r][j], wv[j], s);
      s = wave_reduce_sum(s);
      zr[r] = rmask[r] * (muT / fmaxf(s, 1e-35f));
    }
#pragma unroll
    for (int j = 0; j < 16; ++j) {
      float pj = 0.f;
#pragma unroll
      for (int r = 0; r < 8; ++r) pj = fmaf(e[r][j], zr[r], pj);
      colRed[wave][lane + (j << 6)] = pj;
    }
    __syncthreads();
    for (int n = tid; n < 1024; n += 512) {
      float s = 0.f;
#pragma unroll
      for (int ww = 0; ww < 8; ++ww) s += colRed[ww][n];
      g_store(partP + (g << 10) + n, s);
    }
    ++gen; wg_barrier(ctr, gen << 4);
    for (int n = tid; n < 1024; n += 512) {
      float s = 0.f;
#pragma unroll
      for (int gg = 0; gg < 16; ++gg) s += g_load(partP + (gg << 10) + n);
      wS[n] = nuT / fmaxf(s, 1e-35f);
    }
    __syncthreads();
  }

  {
    float wv[16];
#pragma unroll
    for (int j = 0; j < 16; ++j) wv[j] = wS[lane + (j << 6)];
#pragma unroll
    for (int r = 0; r < 8; ++r) {
      float s = 0.f;
#pragma unroll
      for (int j = 0; j < 16; ++j) {
        const float ee = e[r][j];
        s += (1.f + EPS_OT * __logf(ee)) * ee * wv[j];
      }
      s = wave_reduce_sum(s);
      if (!lane) {
        const int m = (b << 10) + m0 + r;
        z[m] = zr[r];
        attn[m] = 1048576.0f * zr[r] * s;
      }
    }
    for (int n = tid; n < 1024; n += 512) wb[n] = wS[n];
  }
}

// ---------------------------------------------------------------------------
extern "C" void kernel_launch(void* const* d_in, const int* in_sizes, int n_in,
                              void* d_out, int out_size, void* d_ws, size_t ws_size,
                              hipStream_t stream)
{
  const float* xq = (const float*)d_in[0];
  const float* xk = (const float*)d_in[1];
  const float* xv = (const float*)d_in[2];
  const void*  maskRaw = d_in[3];
  const float* Wq = (const float*)d_in[4];
  const float* bq = (const float*)d_in[5];
  const float* Wk = (const float*)d_in[6];
  const float* bk = (const float*)d_in[7];
  const float* Wv = (const float*)d_in[8];
  const float* bv = (const float*)d_in[9];
  const float* Wp = (const float*)d_in[10];
  const float* bp = (const float*)d_in[11];

  float* out  = (float*)d_out;
  float* attn = out + (size_t)NQ * B_DIM * CD;

  char* base = (char*)d_ws;
  // Region map (bytes). Lifetimes ensure overlays never collide:
  const size_t OFF_E   = 0;          // E fp32 33.55MB; pre-sim: xqh/xkh/xvh bf16
  const size_t OFF_QB  = 33554432;   // qb fp32 20.97MB; post-l2: part(1MB) + Et(16.78MB @ +2MB)
  const size_t OFF_KB  = 54525952;   // kb fp32 20.97MB
  const size_t OFF_VP  = 75497472;   // vp fp32 20.97MB; post-vpt: qbh+kbh bf16
  const size_t OFF_VPT = 96468992;   // Vpt bf16 10.49MB
  const size_t OFF_SM  = 106954752;  // weights bf16 + small arrays

  float* E   = (float*)(base + OFF_E);
  u16* xqh   = (u16*)(base + OFF_E);
  u16* xkh   = xqh + (size_t)8192 * CD;
  u16* xvh   = xkh + (size_t)8192 * CD;
  float* qb  = (float*)(base + OFF_QB);
  float* part= (float*)(base + OFF_QB);
  u16* Et    = (u16*)(base + OFF_QB + 2097152);
  float* kb  = (float*)(base + OFF_KB);
  float* vp  = (float*)(base + OFF_VP);
  u16* qbh   = (u16*)(base + OFF_VP);
  u16* kbh   = qbh + (size_t)8192 * CD;
  u16* Vpt   = (u16*)(base + OFF_VPT);
  u16* Wqh   = (u16*)(base + OFF_SM);
  u16* Wkh   = Wqh + CD * CD;
  u16* Ah    = Wkh + CD * CD;
  float* bvp = (float*)(Ah + CD * CD);
  float* z   = bvp + CD;
  float* w   = z + B_DIM * MK;
  int* maskI = (int*)(w + B_DIM * NQ);
  float* muVal = (float*)(maskI + B_DIM * MK);
  unsigned* barCtr = (unsigned*)(muVal + B_DIM);

  k_setup<<<1, 1024, 0, stream>>>(maskRaw, maskI, muVal, w, barCtr);
  k_cvt5<<<dim3(5120, 5), 256, 0, stream>>>(xq, xqh, xk, xkh, xv, xvh,
                                            Wq, Wqh, Wk, Wkh);
  k_combineA<<<dim3(10, 10), 256, 0, stream>>>(Wp, Wv, Ah);
  k_bvp<<<160, 256, 0, stream>>>(Wp, bv, bvp);

  mfma_proj<<<dim3(64, 5, 3), 256, 0, stream>>>(xqh, xkh, xvh, Wqh, Wkh, Ah,
                                                bq, bk, bvp, qb, kb, vp);
  k_vpt<<<dim3(10, 16, 8), 256, 0, stream>>>(vp, Vpt);
  k_l2bf<<<2048, 256, 0, stream>>>(qb, qbh);
  k_l2bf<<<2048, 256, 0, stream>>>(kb, kbh);

  mfma_sim<<<dim3(8, 8, 8), 256, 0, stream>>>(kbh, qbh, E);

  {
    void* args[] = {(void*)&E, (void*)&maskI, (void*)&muVal, (void*)&w,
                    (void*)&z, (void*)&attn, (void*)&part, (void*)&barCtr};
    hipLaunchCooperativeKernel((void*)k_sinkhorn, dim3(128), dim3(512),
                               args, 0, stream);
  }

  k_et<<<dim3(16, 16, 8), 256, 0, stream>>>(E, z, Et);
  mfma_x<<<dim3(8, 5, 8), 256, 0, stream>>>(Et, Vpt, w, bp, out);
}

// Round 7
// 741.873 us; speedup vs baseline: 7.9595x; 1.0988x over previous
//
#include <hip/hip_runtime.h>
#include <cstdint>
#include <cstddef>

#define B_DIM 8
#define NQ    1024
#define MK    1024
#define CD    640
#define INV_EPS 20.0f
#define EPS_OT  0.05f

typedef unsigned short u16;
typedef __attribute__((ext_vector_type(8))) short bf16x8;
typedef __attribute__((ext_vector_type(4))) float f32x4;
typedef __attribute__((ext_vector_type(2))) float f32x2;

#define GLDS(gp, lp) __builtin_amdgcn_global_load_lds( \
    (const __attribute__((address_space(1))) void*)(gp), \
    (__attribute__((address_space(3))) void*)(lp), 16, 0, 0)

static __device__ __forceinline__ float wave_reduce_sum(float s) {
#pragma unroll
  for (int off = 32; off; off >>= 1) s += __shfl_xor(s, off, 64);
  return s;
}

static __device__ __forceinline__ u16 f2bf(float f) {
  uint32_t u = __float_as_uint(f);
  u += 0x7fff + ((u >> 16) & 1);     // RNE
  return (u16)(u >> 16);
}

// Agent-scope (MALL-coherent, placement-independent) relaxed accesses.
// These emit per-access sc1 ops: no L2 writeback/invalidate storms.
static __device__ __forceinline__ void g_store(float* p, float v) {
  __hip_atomic_store(p, v, __ATOMIC_RELAXED, __HIP_MEMORY_SCOPE_AGENT);
}
static __device__ __forceinline__ float g_load(const float* p) {
  return __hip_atomic_load((float*)p, __ATOMIC_RELAXED, __HIP_MEMORY_SCOPE_AGENT);
}
static __device__ __forceinline__ void g_storeu(unsigned* p, unsigned v) {
  __hip_atomic_store(p, v, __ATOMIC_RELAXED, __HIP_MEMORY_SCOPE_AGENT);
}
static __device__ __forceinline__ unsigned g_loadu(const unsigned* p) {
  return __hip_atomic_load((unsigned*)p, __ATOMIC_RELAXED, __HIP_MEMORY_SCOPE_AGENT);
}

// ---------------------------------------------------------------------------
// Setup: detect mask dtype, build maskI, per-batch mu, w=1, zero ctrl block
// ---------------------------------------------------------------------------
__global__ void k_setup(const void* __restrict__ maskRaw, int* __restrict__ maskI,
                        float* __restrict__ muVal, float* __restrict__ w,
                        unsigned* __restrict__ ctrl)
{
  __shared__ int s_flag;
  __shared__ int s_cnt[B_DIM];
  const int tid = threadIdx.x;
  if (tid == 0) s_flag = 0;
  if (tid < B_DIM) s_cnt[tid] = 0;
  ctrl[tid] = 0u;                     // zero flags region (tid < 1024)
  __syncthreads();

  const unsigned char* mb = (const unsigned char*)maskRaw;
  int local = 0;
  for (int i = tid; i < B_DIM * MK; i += 1024)
    if ((i & 3) && mb[i]) local = 1;
  if (local) atomicOr(&s_flag, 1);
  __syncthreads();

  const int isByte = s_flag;
  const int* mi32 = (const int*)maskRaw;
  for (int i = tid; i < B_DIM * MK; i += 1024) {
    int v = isByte ? (int)mb[i] : mi32[i];
    v = v ? 1 : 0;
    maskI[i] = v;
    if (v) atomicAdd(&s_cnt[i >> 10], 1);
  }
  for (int i = tid; i < B_DIM * NQ; i += 1024) w[i] = 1.0f;
  __syncthreads();
  if (tid < B_DIM) {
    float c = (float)s_cnt[tid];
    muVal[tid] = (c > 0.f ? 1.0f / c : 1.0f / (float)MK) + 1e-8f;
  }
}

// ---------------------------------------------------------------------------
// fp32 -> bf16 conversion for xq, xk, xv, Wq, Wk
// ---------------------------------------------------------------------------
__global__ __launch_bounds__(256)
void k_cvt5(const float* __restrict__ x0, u16* __restrict__ d0,
            const float* __restrict__ x1, u16* __restrict__ d1,
            const float* __restrict__ x2, u16* __restrict__ d2,
            const float* __restrict__ x3, u16* __restrict__ d3,
            const float* __restrict__ x4, u16* __restrict__ d4)
{
  const int a = blockIdx.y;
  const float* s; u16* d; int n;
  if      (a == 0) { s = x0; d = d0; n = 8192 * CD; }
  else if (a == 1) { s = x1; d = d1; n = 8192 * CD; }
  else if (a == 2) { s = x2; d = d2; n = 8192 * CD; }
  else if (a == 3) { s = x3; d = d3; n = CD * CD; }
  else             { s = x4; d = d4; n = CD * CD; }
  const int i = (blockIdx.x * 256 + threadIdx.x) * 4;
  if (i >= n) return;
  const float4 v = *(const float4*)(s + i);
  *(ushort4*)(d + i) = make_ushort4(f2bf(v.x), f2bf(v.y), f2bf(v.z), f2bf(v.w));
}

// ---------------------------------------------------------------------------
// Ah = bf16(Wp @ Wv)
// ---------------------------------------------------------------------------
__global__ __launch_bounds__(256)
void k_combineA(const float* __restrict__ Wp, const float* __restrict__ Wv,
                u16* __restrict__ Ah)
{
  __shared__ float Ps[32][68];
  __shared__ float Vs[32][68];
  const int tid = threadIdx.x;
  const int c0 = blockIdx.x << 6, k0 = blockIdx.y << 6;
  const int ty = tid >> 4, tx = tid & 15;
  float acc[4][4];
#pragma unroll
  for (int i = 0; i < 4; ++i)
#pragma unroll
    for (int j = 0; j < 4; ++j) acc[i][j] = 0.f;

  for (int j0 = 0; j0 < CD; j0 += 32) {
    {
      const int c = tid >> 2, j4 = (tid & 3) << 3;
      const float* p = Wp + (size_t)(c0 + c) * CD + j0 + j4;
      float4 u0 = *(const float4*)p, u1 = *(const float4*)(p + 4);
      Ps[j4 + 0][c] = u0.x; Ps[j4 + 1][c] = u0.y; Ps[j4 + 2][c] = u0.z; Ps[j4 + 3][c] = u0.w;
      Ps[j4 + 4][c] = u1.x; Ps[j4 + 5][c] = u1.y; Ps[j4 + 6][c] = u1.z; Ps[j4 + 7][c] = u1.w;
    }
    {
      const int j = tid >> 3, k4 = (tid & 7) << 3;
      const float* p = Wv + (size_t)(j0 + j) * CD + k0 + k4;
      float4 u0 = *(const float4*)p, u1 = *(const float4*)(p + 4);
      *(float4*)&Vs[j][k4] = u0; *(float4*)&Vs[j][k4 + 4] = u1;
    }
    __syncthreads();
#pragma unroll
    for (int j = 0; j < 32; ++j) {
      float a[4], b[4];
      *(float4*)a = *(const float4*)&Ps[j][ty << 2];
      *(float4*)b = *(const float4*)&Vs[j][tx << 2];
#pragma unroll
      for (int i = 0; i < 4; ++i)
#pragma unroll
        for (int jj = 0; jj < 4; ++jj)
          acc[i][jj] = fmaf(a[i], b[jj], acc[i][jj]);
    }
    __syncthreads();
  }
#pragma unroll
  for (int i = 0; i < 4; ++i) {
    *(ushort4*)(Ah + (size_t)(c0 + (ty << 2) + i) * CD + k0 + (tx << 2)) =
      make_ushort4(f2bf(acc[i][0]), f2bf(acc[i][1]), f2bf(acc[i][2]), f2bf(acc[i][3]));
  }
}

// bvp[c] = sum_j Wp[c][j]*bv[j]
__global__ __launch_bounds__(256)
void k_bvp(const float* __restrict__ Wp, const float* __restrict__ bv,
           float* __restrict__ bvp)
{
  const int c = (blockIdx.x << 2) + (threadIdx.x >> 6);
  const int lane = threadIdx.x & 63;
  float s = 0.f;
  for (int j = lane; j < CD; j += 64) s = fmaf(Wp[(size_t)c * CD + j], bv[j], s);
  s = wave_reduce_sum(s);
  if (!lane) bvp[c] = s;
}

// ---------------------------------------------------------------------------
// MFMA NT GEMMs (unchanged from round 5)
// ---------------------------------------------------------------------------
__global__ __launch_bounds__(256)
void mfma_proj(const u16* __restrict__ xqh, const u16* __restrict__ xkh,
               const u16* __restrict__ xvh,
               const u16* __restrict__ Wqh, const u16* __restrict__ Wkh,
               const u16* __restrict__ Ah,
               const float* __restrict__ bq, const float* __restrict__ bk,
               const float* __restrict__ bvp,
               float* __restrict__ qb, float* __restrict__ kb,
               float* __restrict__ vp)
{
  __shared__ u16 As[128 * 32];
  __shared__ u16 Bs[128 * 32];
  const int mode = blockIdx.z;
  const u16* X     = (mode == 0) ? xqh : ((mode == 1) ? xkh : xvh);
  const u16* W     = (mode == 0) ? Wqh : ((mode == 1) ? Wkh : Ah);
  const float* bias= (mode == 0) ? bq  : ((mode == 1) ? bk  : bvp);
  float* outp      = (mode == 0) ? qb  : ((mode == 1) ? kb  : vp);

  const int tid = threadIdx.x, wave = tid >> 6, lane = tid & 63;
  const int row0 = blockIdx.x << 7, col0 = blockIdx.y << 7;

  const int rS = (wave << 5) + (lane >> 2);
  const int pc = lane & 3;
  const int kc0 = pc ^ ((rS >> 1) & 3);
  const int kc1 = pc ^ (((rS + 16) >> 1) & 3);
  const u16* gA0 = X + (size_t)(row0 + rS) * CD + (kc0 << 3);
  const u16* gA1 = X + (size_t)(row0 + rS + 16) * CD + (kc1 << 3);
  const u16* gB0 = W + (size_t)(col0 + rS) * CD + (kc0 << 3);
  const u16* gB1 = W + (size_t)(col0 + rS + 16) * CD + (kc1 << 3);
  u16* lA = As + (wave << 10);
  u16* lB = Bs + (wave << 10);

  const int wm0 = (wave & 1) << 6, wn0 = (wave >> 1) << 6;
  int aOff[4], bOff[4];
#pragma unroll
  for (int t = 0; t < 4; ++t) {
    const int ra = wm0 + (t << 4) + (lane & 15);
    aOff[t] = ra * 32 + (((lane >> 4) ^ ((ra >> 1) & 3)) << 3);
    const int rb = wn0 + (t << 4) + (lane & 15);
    bOff[t] = rb * 32 + (((lane >> 4) ^ ((rb >> 1) & 3)) << 3);
  }
  f32x4 acc[4][4];
#pragma unroll
  for (int i = 0; i < 4; ++i)
#pragma unroll
    for (int j = 0; j < 4; ++j) acc[i][j] = {0.f, 0.f, 0.f, 0.f};

  for (int k0 = 0; k0 < CD; k0 += 32) {
    __syncthreads();
    GLDS(gA0, lA); GLDS(gA1, lA + 512);
    GLDS(gB0, lB); GLDS(gB1, lB + 512);
    gA0 += 32; gA1 += 32; gB0 += 32; gB1 += 32;
    __syncthreads();
    bf16x8 a[4], b[4];
#pragma unroll
    for (int t = 0; t < 4; ++t) {
      a[t] = *(const bf16x8*)(As + aOff[t]);
      b[t] = *(const bf16x8*)(Bs + bOff[t]);
    }
#pragma unroll
    for (int i = 0; i < 4; ++i)
#pragma unroll
      for (int j = 0; j < 4; ++j)
        acc[i][j] = __builtin_amdgcn_mfma_f32_16x16x32_bf16(a[i], b[j], acc[i][j], 0, 0, 0);
  }

  float bv4[4];
  int ccs[4];
#pragma unroll
  for (int j = 0; j < 4; ++j) {
    ccs[j] = col0 + wn0 + (j << 4) + (lane & 15);
    bv4[j] = bias[ccs[j]];
  }
#pragma unroll
  for (int i = 0; i < 4; ++i) {
    const int rbase = row0 + wm0 + (i << 4) + ((lane >> 4) << 2);
#pragma unroll
    for (int r = 0; r < 4; ++r) {
      const int rr = rbase + r;
      const size_t orow = (mode == 0) ? ((size_t)(rr & 7) * NQ + (rr >> 3)) : (size_t)rr;
      float* op = outp + orow * CD;
#pragma unroll
      for (int j = 0; j < 4; ++j)
        op[ccs[j]] = acc[i][j][r] + bv4[j];
    }
  }
}

__global__ __launch_bounds__(256)
void mfma_sim(const u16* __restrict__ kbh, const u16* __restrict__ qbh,
              float* __restrict__ E)
{
  __shared__ u16 As[128 * 32];
  __shared__ u16 Bs[128 * 32];
  const int tid = threadIdx.x, wave = tid >> 6, lane = tid & 63;
  const int b = blockIdx.z;
  const int row0 = blockIdx.x << 7, col0 = blockIdx.y << 7;
  const u16* A = kbh + (size_t)b * MK * CD;
  const u16* B = qbh + (size_t)b * NQ * CD;

  const int rS = (wave << 5) + (lane >> 2);
  const int pc = lane & 3;
  const int kc0 = pc ^ ((rS >> 1) & 3);
  const int kc1 = pc ^ (((rS + 16) >> 1) & 3);
  const u16* gA0 = A + (size_t)(row0 + rS) * CD + (kc0 << 3);
  const u16* gA1 = A + (size_t)(row0 + rS + 16) * CD + (kc1 << 3);
  const u16* gB0 = B + (size_t)(col0 + rS) * CD + (kc0 << 3);
  const u16* gB1 = B + (size_t)(col0 + rS + 16) * CD + (kc1 << 3);
  u16* lA = As + (wave << 10);
  u16* lB = Bs + (wave << 10);

  const int wm0 = (wave & 1) << 6, wn0 = (wave >> 1) << 6;
  int aOff[4], bOff[4];
#pragma unroll
  for (int t = 0; t < 4; ++t) {
    const int ra = wm0 + (t << 4) + (lane & 15);
    aOff[t] = ra * 32 + (((lane >> 4) ^ ((ra >> 1) & 3)) << 3);
    const int rb = wn0 + (t << 4) + (lane & 15);
    bOff[t] = rb * 32 + (((lane >> 4) ^ ((rb >> 1) & 3)) << 3);
  }
  f32x4 acc[4][4];
#pragma unroll
  for (int i = 0; i < 4; ++i)
#pragma unroll
    for (int j = 0; j < 4; ++j) acc[i][j] = {0.f, 0.f, 0.f, 0.f};

  for (int k0 = 0; k0 < CD; k0 += 32) {
    __syncthreads();
    GLDS(gA0, lA); GLDS(gA1, lA + 512);
    GLDS(gB0, lB); GLDS(gB1, lB + 512);
    gA0 += 32; gA1 += 32; gB0 += 32; gB1 += 32;
    __syncthreads();
    bf16x8 a[4], b[4];
#pragma unroll
    for (int t = 0; t < 4; ++t) {
      a[t] = *(const bf16x8*)(As + aOff[t]);
      b[t] = *(const bf16x8*)(Bs + bOff[t]);
    }
#pragma unroll
    for (int i = 0; i < 4; ++i)
#pragma unroll
      for (int j = 0; j < 4; ++j)
        acc[i][j] = __builtin_amdgcn_mfma_f32_16x16x32_bf16(a[i], b[j], acc[i][j], 0, 0, 0);
  }

#pragma unroll
  for (int i = 0; i < 4; ++i) {
    const int rbase = row0 + wm0 + (i << 4) + ((lane >> 4) << 2);
#pragma unroll
    for (int r = 0; r < 4; ++r) {
      const int rr = rbase + r;
      float* erow = E + (((size_t)(b << 10) + rr) << 10);
#pragma unroll
      for (int j = 0; j < 4; ++j) {
        const int cc = col0 + wn0 + (j << 4) + (lane & 15);
        erow[cc] = __expf((acc[i][j][r] - 1.f) * INV_EPS);
      }
    }
  }
}

__global__ __launch_bounds__(256)
void mfma_x(const u16* __restrict__ Et, const u16* __restrict__ Vpt,
            const float* __restrict__ w, const float* __restrict__ bp,
            float* __restrict__ out)
{
  __shared__ u16 As[128 * 32];
  __shared__ u16 Bs[128 * 32];
  const int tid = threadIdx.x, wave = tid >> 6, lane = tid & 63;
  const int b = blockIdx.z;
  const int row0 = blockIdx.x << 7;
  const int col0 = blockIdx.y << 7;
  const u16* A = Et + ((size_t)b << 20);
  const u16* B = Vpt + (size_t)b * CD * MK;

  const int rS = (wave << 5) + (lane >> 2);
  const int pc = lane & 3;
  const int kc0 = pc ^ ((rS >> 1) & 3);
  const int kc1 = pc ^ (((rS + 16) >> 1) & 3);
  const u16* gA0 = A + ((size_t)(row0 + rS) << 10) + (kc0 << 3);
  const u16* gA1 = A + ((size_t)(row0 + rS + 16) << 10) + (kc1 << 3);
  const u16* gB0 = B + ((size_t)(col0 + rS) << 10) + (kc0 << 3);
  const u16* gB1 = B + ((size_t)(col0 + rS + 16) << 10) + (kc1 << 3);
  u16* lA = As + (wave << 10);
  u16* lB = Bs + (wave << 10);

  const int wm0 = (wave & 1) << 6, wn0 = (wave >> 1) << 6;
  int aOff[4], bOff[4];
#pragma unroll
  for (int t = 0; t < 4; ++t) {
    const int ra = wm0 + (t << 4) + (lane & 15);
    aOff[t] = ra * 32 + (((lane >> 4) ^ ((ra >> 1) & 3)) << 3);
    const int rb = wn0 + (t << 4) + (lane & 15);
    bOff[t] = rb * 32 + (((lane >> 4) ^ ((rb >> 1) & 3)) << 3);
  }
  f32x4 acc[4][4];
#pragma unroll
  for (int i = 0; i < 4; ++i)
#pragma unroll
    for (int j = 0; j < 4; ++j) acc[i][j] = {0.f, 0.f, 0.f, 0.f};

  for (int k0 = 0; k0 < MK; k0 += 32) {
    __syncthreads();
    GLDS(gA0, lA); GLDS(gA1, lA + 512);
    GLDS(gB0, lB); GLDS(gB1, lB + 512);
    gA0 += 32; gA1 += 32; gB0 += 32; gB1 += 32;
    __syncthreads();
    bf16x8 a[4], b[4];
#pragma unroll
    for (int t = 0; t < 4; ++t) {
      a[t] = *(const bf16x8*)(As + aOff[t]);
      b[t] = *(const bf16x8*)(Bs + bOff[t]);
    }
#pragma unroll
    for (int i = 0; i < 4; ++i)
#pragma unroll
      for (int j = 0; j < 4; ++j)
        acc[i][j] = __builtin_amdgcn_mfma_f32_16x16x32_bf16(a[i], b[j], acc[i][j], 0, 0, 0);
  }

  float bv4[4];
  int ccs[4];
#pragma unroll
  for (int j = 0; j < 4; ++j) {
    ccs[j] = col0 + wn0 + (j << 4) + (lane & 15);
    bv4[j] = bp[ccs[j]];
  }
#pragma unroll
  for (int i = 0; i < 4; ++i) {
    const int rbase = row0 + wm0 + (i << 4) + ((lane >> 4) << 2);
#pragma unroll
    for (int r = 0; r < 4; ++r) {
      const int rr = rbase + r;
      const float wn = w[(b << 10) + rr];
      float* op = out + ((size_t)rr * 8 + b) * CD;
#pragma unroll
      for (int j = 0; j < 4; ++j)
        op[ccs[j]] = acc[i][j][r] * wn + bv4[j];
    }
  }
}

// ---------------------------------------------------------------------------
// l2norm rows of 640 fp32 -> bf16 output
// ---------------------------------------------------------------------------
__global__ __launch_bounds__(256)
void k_l2bf(const float* __restrict__ X, u16* __restrict__ O)
{
  const int row = (blockIdx.x << 2) + (threadIdx.x >> 6);
  const int lane = threadIdx.x & 63;
  const float2* p2 = (const float2*)(X + (size_t)row * CD);
  float2 v[5];
  float ss = 0.f;
#pragma unroll
  for (int i = 0; i < 5; ++i) {
    v[i] = p2[lane + (i << 6)];
    ss = fmaf(v[i].x, v[i].x, fmaf(v[i].y, v[i].y, ss));
  }
  ss = wave_reduce_sum(ss);
  const float inv = 1.0f / fmaxf(sqrtf(ss), 1e-12f);
  ushort2* o2 = (ushort2*)(O + (size_t)row * CD);
#pragma unroll
  for (int i = 0; i < 5; ++i)
    o2[lane + (i << 6)] = make_ushort2(f2bf(v[i].x * inv), f2bf(v[i].y * inv));
}

// ---------------------------------------------------------------------------
// Transposes (unchanged)
// ---------------------------------------------------------------------------
__global__ __launch_bounds__(256)
void k_vpt(const float* __restrict__ vp, u16* __restrict__ Vpt)
{
  __shared__ float t[64][65];
  const int b = blockIdx.z, m0 = blockIdx.y << 6, c0 = blockIdx.x << 6;
  const int tid = threadIdx.x;
  const int cc = tid & 63, r4 = tid >> 6;
#pragma unroll
  for (int i = 0; i < 16; ++i) {
    const int m = (i << 2) + r4;
    t[m][cc] = vp[((size_t)((b << 10) + m0 + m)) * CD + c0 + cc];
  }
  __syncthreads();
  const int mm = tid & 63;
#pragma unroll
  for (int i = 0; i < 16; ++i) {
    const int c = (i << 2) + r4;
    Vpt[((size_t)(b * CD + c0 + c) << 10) + m0 + mm] = f2bf(t[mm][c]);
  }
}

__global__ __launch_bounds__(256)
void k_et(const float* __restrict__ E, const float* __restrict__ z,
          u16* __restrict__ Et)
{
  __shared__ float t[64][65];
  const int b = blockIdx.z, m0 = blockIdx.y << 6, n0 = blockIdx.x << 6;
  const int tid = threadIdx.x;
  const int nn = tid & 63, r4 = tid >> 6;
#pragma unroll
  for (int i = 0; i < 16; ++i) {
    const int m = (i << 2) + r4;
    const float zm = z[(b << 10) + m0 + m];
    t[m][nn] = E[(((size_t)((b << 10) + m0 + m)) << 10) + n0 + nn] * zm;
  }
  __syncthreads();
  const int mm = tid & 63;
#pragma unroll
  for (int i = 0; i < 16; ++i) {
    const int n = (i << 2) + r4;
    Et[(((size_t)((b << 10) + n0 + n)) << 10) + m0 + mm] = f2bf(t[mm][n]);
  }
}

// ---------------------------------------------------------------------------
// Fused persistent Sinkhorn v4: 128 WGs x 512 thr, 64 E-rows/WG in registers.
// One exchange per iteration: publish partial slice -> per-WG FLAG store
// (no RMW serialization) -> parallel 16-flag poll -> gather. All cross-WG
// traffic via agent-scope relaxed atomics (placement-independent, G16-safe).
// ---------------------------------------------------------------------------
__global__ __launch_bounds__(512, 2)
void k_sinkhorn(const float* __restrict__ E, const int* __restrict__ maskI,
                const float* __restrict__ muVal, float* __restrict__ w,
                float* __restrict__ z, float* __restrict__ attn,
                float* __restrict__ part, unsigned* __restrict__ ctrl)
{
  const int b = blockIdx.x & 7;        // XCD-affinity swizzle (perf heuristic only)
  const int g = blockIdx.x >> 3;       // 0..15
  const int tid = threadIdx.x;
  const int wave = tid >> 6, lane = tid & 63;
  const int m0 = (g << 6) + (wave << 3);
  const float* Eb = E + ((size_t)b << 20);
  float* wb = w + (b << 10);
  unsigned* flagB = ctrl + 64 + (b << 6);   // 16 flags per batch, 256B stride

  __shared__ float wS[1024];
  __shared__ float colRed[8][1024];

  // load 64 rows into registers
  float e[8][16];
#pragma unroll
  for (int r = 0; r < 8; ++r) {
    const float* row = Eb + ((size_t)(m0 + r) << 10) + lane;
#pragma unroll
    for (int j = 0; j < 16; ++j) e[r][j] = row[j << 6];
  }
  float rmask[8];
#pragma unroll
  for (int r = 0; r < 8; ++r)
    rmask[r] = maskI[(b << 10) + m0 + r] ? 1.f : 0.f;
  const float muT = muVal[b];
  const float nuT = 1.0f / (float)NQ + 1e-8f;
  float zr[8];
#pragma unroll
  for (int r = 0; r < 8; ++r) zr[r] = 0.f;

  wS[tid] = 1.0f; wS[tid + 512] = 1.0f;
  __syncthreads();

  for (int it = 0; it < 100; ++it) {
    // parity double-buffer for partials: barrier separates read(p) / write(p)
    float* partP = part + (size_t)((((it & 1) << 3) + b) << 14);  // [16][1024]
    // u-phase
    float wv[16];
#pragma unroll
    for (int j = 0; j < 16; ++j) wv[j] = wS[lane + (j << 6)];
#pragma unroll
    for (int r = 0; r < 8; ++r) {
      float s = 0.f;
#pragma unroll
      for (int j = 0; j < 16; ++j) s = fmaf(e[r][j], wv[j], s);
      s = wave_reduce_sum(s);
      zr[r] = rmask[r] * (muT / fmaxf(s, 1e-35f));
    }
    // column partials -> LDS per wave
#pragma unroll
    for (int j = 0; j < 16; ++j) {
      float pj = 0.f;
#pragma unroll
      for (int r = 0; r < 8; ++r) pj = fmaf(e[r][j], zr[r], pj);
      colRed[wave][lane + (j << 6)] = pj;
    }
    __syncthreads();
    // reduce 8 waves, publish WG's contiguous 1024-float partial slice
    for (int n = tid; n < 1024; n += 512) {
      float s = 0.f;
#pragma unroll
      for (int w8 = 0; w8 < 8; ++w8) s += colRed[w8][n];
      g_store(partP + (g << 10) + n, s);
    }
    __syncthreads();                       // drains vmcnt: publishes complete
    const unsigned gen = (unsigned)(it + 1);
    if (tid == 0) g_storeu(flagB + g, gen);            // independent flag store
    if (wave == 0 && lane < 16) {                      // parallel 16-flag poll
      while (g_loadu(flagB + lane) < gen)
        __builtin_amdgcn_s_sleep(1);
    }
    __syncthreads();
    __builtin_amdgcn_fence(__ATOMIC_ACQUIRE, "workgroup");  // compiler ordering
    // gather: each thread sums the 16 partials for n=tid and n=tid+512
    {
      float s0 = 0.f, s1 = 0.f;
#pragma unroll
      for (int gg = 0; gg < 16; ++gg) {
        s0 += g_load(partP + (gg << 10) + tid);
        s1 += g_load(partP + (gg << 10) + tid + 512);
      }
      wS[tid]       = nuT / fmaxf(s0, 1e-35f);
      wS[tid + 512] = nuT / fmaxf(s1, 1e-35f);
    }
    __syncthreads();
  }

  // epilogue: attn + z with final z (iter-100 u) and final w (iter-100 v, in wS)
  {
    float wv[16];
#pragma unroll
    for (int j = 0; j < 16; ++j) wv[j] = wS[lane + (j << 6)];
#pragma unroll
    for (int r = 0; r < 8; ++r) {
      float s = 0.f;
#pragma unroll
      for (int j = 0; j < 16; ++j) {
        const float ee = e[r][j];
        s += (1.f + EPS_OT * __logf(ee)) * ee * wv[j];
      }
      s = wave_reduce_sum(s);
      if (!lane) {
        const int m = (b << 10) + m0 + r;
        z[m] = zr[r];
        attn[m] = 1048576.0f * zr[r] * s;
      }
    }
    for (int n = tid; n < 1024; n += 512) wb[n] = wS[n];
  }
}

// ---------------------------------------------------------------------------
extern "C" void kernel_launch(void* const* d_in, const int* in_sizes, int n_in,
                              void* d_out, int out_size, void* d_ws, size_t ws_size,
                              hipStream_t stream)
{
  const float* xq = (const float*)d_in[0];
  const float* xk = (const float*)d_in[1];
  const float* xv = (const float*)d_in[2];
  const void*  maskRaw = d_in[3];
  const float* Wq = (const float*)d_in[4];
  const float* bq = (const float*)d_in[5];
  const float* Wk = (const float*)d_in[6];
  const float* bk = (const float*)d_in[7];
  const float* Wv = (const float*)d_in[8];
  const float* bv = (const float*)d_in[9];
  const float* Wp = (const float*)d_in[10];
  const float* bp = (const float*)d_in[11];

  float* out  = (float*)d_out;
  float* attn = out + (size_t)NQ * B_DIM * CD;

  char* base = (char*)d_ws;
  const size_t OFF_E   = 0;          // E fp32 33.55MB; pre-sim: xqh/xkh/xvh bf16
  const size_t OFF_QB  = 33554432;   // qb fp32; post-l2: part(1MB) + Et(@ +2MB)
  const size_t OFF_KB  = 54525952;   // kb fp32
  const size_t OFF_VP  = 75497472;   // vp fp32; post-vpt: qbh+kbh bf16
  const size_t OFF_VPT = 96468992;   // Vpt bf16 10.49MB
  const size_t OFF_SM  = 106954752;  // weights bf16 + small arrays

  float* E   = (float*)(base + OFF_E);
  u16* xqh   = (u16*)(base + OFF_E);
  u16* xkh   = xqh + (size_t)8192 * CD;
  u16* xvh   = xkh + (size_t)8192 * CD;
  float* qb  = (float*)(base + OFF_QB);
  float* part= (float*)(base + OFF_QB);
  u16* Et    = (u16*)(base + OFF_QB + 2097152);
  float* kb  = (float*)(base + OFF_KB);
  float* vp  = (float*)(base + OFF_VP);
  u16* qbh   = (u16*)(base + OFF_VP);
  u16* kbh   = qbh + (size_t)8192 * CD;
  u16* Vpt   = (u16*)(base + OFF_VPT);
  u16* Wqh   = (u16*)(base + OFF_SM);
  u16* Wkh   = Wqh + CD * CD;
  u16* Ah    = Wkh + CD * CD;
  float* bvp = (float*)(Ah + CD * CD);
  float* z   = bvp + CD;
  float* w   = z + B_DIM * MK;
  int* maskI = (int*)(w + B_DIM * NQ);
  float* muVal = (float*)(maskI + B_DIM * MK);
  unsigned* ctrl = (unsigned*)(muVal + B_DIM);   // [1024]: flags at +64

  k_setup<<<1, 1024, 0, stream>>>(maskRaw, maskI, muVal, w, ctrl);
  k_cvt5<<<dim3(5120, 5), 256, 0, stream>>>(xq, xqh, xk, xkh, xv, xvh,
                                            Wq, Wqh, Wk, Wkh);
  k_combineA<<<dim3(10, 10), 256, 0, stream>>>(Wp, Wv, Ah);
  k_bvp<<<160, 256, 0, stream>>>(Wp, bv, bvp);

  mfma_proj<<<dim3(64, 5, 3), 256, 0, stream>>>(xqh, xkh, xvh, Wqh, Wkh, Ah,
                                                bq, bk, bvp, qb, kb, vp);
  k_vpt<<<dim3(10, 16, 8), 256, 0, stream>>>(vp, Vpt);
  k_l2bf<<<2048, 256, 0, stream>>>(qb, qbh);
  k_l2bf<<<2048, 256, 0, stream>>>(kb, kbh);

  mfma_sim<<<dim3(8, 8, 8), 256, 0, stream>>>(kbh, qbh, E);

  {
    void* args[] = {(void*)&E, (void*)&maskI, (void*)&muVal, (void*)&w,
                    (void*)&z, (void*)&attn, (void*)&part, (void*)&ctrl};
    hipLaunchCooperativeKernel((void*)k_sinkhorn, dim3(128), dim3(512),
                               args, 0, stream);
  }

  k_et<<<dim3(16, 16, 8), 256, 0, stream>>>(E, z, Et);
  mfma_x<<<dim3(8, 5, 8), 256, 0, stream>>>(Et, Vpt, w, bp, out);
}